// Round 1
// baseline (1666.383 us; speedup 1.0000x reference)
//
#include <hip/hip_runtime.h>

typedef unsigned short u16;
typedef unsigned int   u32;

#define BATCH   2
#define SEQ     2048
#define DMODEL  4096
#define NHEADS  32
#define NKV     8
#define HDIM    128
#define QKV_DIM 6144

typedef __bf16 bf16x8 __attribute__((ext_vector_type(8)));
typedef float  f32x4  __attribute__((ext_vector_type(4)));

__device__ __forceinline__ float b2f(u16 u) {
  u32 x = ((u32)u) << 16;
  return __builtin_bit_cast(float, x);
}
__device__ __forceinline__ u16 f2b(float f) {
  u32 x = __builtin_bit_cast(u32, f);
  x = (x + 0x7FFFu + ((x >> 16) & 1u)) >> 16;  // RNE
  return (u16)x;
}
__device__ __forceinline__ float b2f_lo(u32 p) { return __builtin_bit_cast(float, p << 16); }
__device__ __forceinline__ float b2f_hi(u32 p) { return __builtin_bit_cast(float, p & 0xFFFF0000u); }

__device__ __forceinline__ u32 pk(float a, float b) {
  return (u32)f2b(a) | ((u32)f2b(b) << 16);
}

// stage 16 contiguous elements (converting to bf16 if fp32) into LDS
__device__ __forceinline__ void stage16(const float* __restrict__ g, u16* __restrict__ lds) {
  const float4* p = (const float4*)g;
  float4 a = p[0], b = p[1], c = p[2], d = p[3];
  uint4 r0, r1;
  r0.x = pk(a.x, a.y); r0.y = pk(a.z, a.w); r0.z = pk(b.x, b.y); r0.w = pk(b.z, b.w);
  r1.x = pk(c.x, c.y); r1.y = pk(c.z, c.w); r1.z = pk(d.x, d.y); r1.w = pk(d.z, d.w);
  ((uint4*)lds)[0] = r0;
  ((uint4*)lds)[1] = r1;
}
__device__ __forceinline__ void stage16(const u16* __restrict__ g, u16* __restrict__ lds) {
  const uint4* p = (const uint4*)g;
  ((uint4*)lds)[0] = p[0];
  ((uint4*)lds)[1] = p[1];
}

// ---------------------------------------------------------------------------
// GEMM: C[m][n] = sum_k A[m][k] * W[n][k] + bias[n]   (B^T-input form)
// 128x128 tile, 4 waves, BK=32, mfma_f32_16x16x32_bf16, fp32 accumulate.
// MODE 0: scatter epilogue into bf16 Q/K/V [b,h,s,d]. MODE 1: fp32 C + bias.
// ---------------------------------------------------------------------------
template <int MODE, typename TA, typename TB>
__global__ __launch_bounds__(256) void gemm_bt(const TA* __restrict__ A,
                                               const TB* __restrict__ Bw,
                                               const float* __restrict__ bias,
                                               float* __restrict__ outf,
                                               u16* __restrict__ oq,
                                               u16* __restrict__ ok,
                                               u16* __restrict__ ov,
                                               int K, int N) {
  __shared__ u16 As[128 * 32];
  __shared__ u16 Bs[128 * 32];
  const int t    = threadIdx.x;
  const int lane = t & 63;
  const int wv   = t >> 6;
  const int wr   = wv >> 1, wc = wv & 1;
  const int m0   = blockIdx.y * 128, n0 = blockIdx.x * 128;

  f32x4 acc[4][4] = {};

  const int sr = t >> 1, sc = (t & 1) * 16;
  const TA* gA = A  + (size_t)(m0 + sr) * K + sc;
  const TB* gB = Bw + (size_t)(n0 + sr) * K + sc;
  u16* lA = &As[sr * 32 + sc];
  u16* lB = &Bs[sr * 32 + sc];

  const int kq   = (lane >> 4) * 8;
  const int arow = (wr * 64 + (lane & 15)) * 32 + kq;
  const int brow = (wc * 64 + (lane & 15)) * 32 + kq;

  for (int k0 = 0; k0 < K; k0 += 32) {
    __syncthreads();
    stage16(gA + k0, lA);
    stage16(gB + k0, lB);
    __syncthreads();

    bf16x8 af[4], bfr[4];
#pragma unroll
    for (int i = 0; i < 4; i++) af[i] = *(const bf16x8*)&As[arow + i * 512];
#pragma unroll
    for (int j = 0; j < 4; j++) bfr[j] = *(const bf16x8*)&Bs[brow + j * 512];
#pragma unroll
    for (int i = 0; i < 4; i++)
#pragma unroll
      for (int j = 0; j < 4; j++)
        acc[i][j] = __builtin_amdgcn_mfma_f32_16x16x32_bf16(af[i], bfr[j], acc[i][j], 0, 0, 0);
  }

  const int col = lane & 15, quad = lane >> 4;
#pragma unroll
  for (int j = 0; j < 4; j++) {
    const int gn = n0 + wc * 64 + j * 16 + col;
    const float bv = bias[gn];
#pragma unroll
    for (int i = 0; i < 4; i++) {
      const int gmb = m0 + wr * 64 + i * 16 + quad * 4;
#pragma unroll
      for (int rr = 0; rr < 4; rr++) {
        const float val = acc[i][j][rr] + bv;
        const int gm = gmb + rr;
        if (MODE == 1) {
          outf[(size_t)gm * N + gn] = val;
        } else {
          const int b = gm >> 11, s = gm & (SEQ - 1);
          const int d = gn & (HDIM - 1);
          if (gn < 4096) {
            const int hh = gn >> 7;
            oq[((size_t)(b * NHEADS + hh) * SEQ + s) * HDIM + d] = f2b(val);
          } else if (gn < 5120) {
            const int hh = (gn - 4096) >> 7;
            ok[((size_t)(b * NKV + hh) * SEQ + s) * HDIM + d] = f2b(val);
          } else {
            const int hh = (gn - 5120) >> 7;
            ov[((size_t)(b * NKV + hh) * SEQ + s) * HDIM + d] = f2b(val);
          }
        }
      }
    }
  }
}

// ---------------------------------------------------------------------------
// RoPE in place on bf16 Q and K; cos/sin in fp32.
// ---------------------------------------------------------------------------
__global__ __launch_bounds__(256) void rope_kernel(u16* __restrict__ q, u16* __restrict__ kk,
                                                   int qrows, int totrows) {
  const int idx = blockIdx.x * 256 + threadIdx.x;
  const int row = idx >> 6;
  const int i   = idx & 63;
  if (row >= totrows) return;
  u16* base;
  int r;
  if (row < qrows) { base = q  + (size_t)row * HDIM;           r = row; }
  else             { base = kk + (size_t)(row - qrows) * HDIM; r = row - qrows; }
  const int s = r & (SEQ - 1);
  const float l2theta = 13.287712379549449f;  // log2(10000)
  const float inv = exp2f(-((float)(2 * i) * (1.0f / 128.0f)) * l2theta);
  const float ang = (float)s * inv;
  const float c  = cosf(ang);
  const float sn = sinf(ang);
  const u32 xv = *(const u32*)&base[2 * i];
  const float xr = b2f_lo(xv), xi = b2f_hi(xv);
  *(u32*)&base[2 * i] = pk(xr * c - xi * sn, xr * sn + xi * c);
}

// ---------------------------------------------------------------------------
// MFMA flash attention (causal, GQA group=4).
// Block: 128 q-rows, 4 waves x 32 rows (2 row-tiles of 16). K-chunk = 64 keys.
// This round (T14 + deferred-l + full-chunk fast path):
//  * K/V tiles for chunk kc+1 are prefetched into REGISTERS while chunk kc is
//    being computed; regs are committed to LDS at the top of the next
//    iteration (plain register loads stay in flight across __syncthreads).
//  * l (softmax denominator) is kept as per-lane PARTIAL sums; the 16-lane
//    reduction happens once in the epilogue instead of 4 shfl_xor per row per
//    chunk (alpha is quad-uniform so partials scale identically).
//  * chunks entirely below the causal diagonal skip the key<=mm masking ops
//    (wave-uniform branch).
// ---------------------------------------------------------------------------
__global__ __launch_bounds__(256) void attn_mfma(const u16* __restrict__ q,
                                                 const u16* __restrict__ k,
                                                 const u16* __restrict__ v,
                                                 u16* __restrict__ out) {
  __shared__ u16 Ks[64 * 136];       // [key][d], stride 136 u16 (272B, 16B-mult)
  __shared__ u16 VtBuf[128 * 72];    // [d][key-swizzled], stride 72 u16 (144B)
  __shared__ u16 Ps[4 * 32 * 72];    // per wave: [row][key], stride 72 u16
  u32* Vt32 = (u32*)VtBuf;           // row stride 36 u32

  const int t    = threadIdx.x;
  const int lane = t & 63;
  const int w    = t >> 6;
  const int q4   = lane >> 4, l15 = lane & 15;
  const int qb   = 15 - (int)blockIdx.x;   // heavy blocks first
  const int h = blockIdx.y, b = blockIdx.z;
  const int m0 = qb * 128;
  const int mw = m0 + w * 32;              // wave's first q-row
  const int kvh = h >> 2;
  const u16* Qp = q + (size_t)(b * NHEADS + h) * SEQ * HDIM;
  const u16* Kp = k + (size_t)(b * NKV + kvh) * SEQ * HDIM;
  const u16* Vp = v + (size_t)(b * NKV + kvh) * SEQ * HDIM;
  const float scale = 0.08838834764831845f;  // 1/sqrt(128)

  // Q fragments (held in registers for the whole kernel)
  bf16x8 qf[2][4];
#pragma unroll
  for (int rt = 0; rt < 2; rt++)
#pragma unroll
    for (int kk = 0; kk < 4; kk++)
      qf[rt][kk] = *(const bf16x8*)&Qp[(size_t)(mw + rt * 16 + l15) * HDIM + kk * 32 + q4 * 8];

  f32x4 oacc[2][8] = {};
  float mrow[2][4], lrow[2][4];
#pragma unroll
  for (int rt = 0; rt < 2; rt++)
#pragma unroll
    for (int rr = 0; rr < 4; rr++) { mrow[rt][rr] = -1e30f; lrow[rt][rr] = 0.f; }

  u16* Pw = &Ps[w * 32 * 72];

  // ---- register prefetch staging (T14): K tile 64B/thread, V tile 16B/thread
  uint4 kreg[4];
  uint2 vreg[4][2];
  auto loadKV = [&](int kc0) {
#pragma unroll
    for (int i = 0; i < 4; i++) {
      const int u = t + i * 256;           // 1024 units of 16B
      const int r = u >> 4, c = (u & 15) * 8;
      kreg[i] = *(const uint4*)&Kp[(size_t)(kc0 * 64 + r) * HDIM + c];
    }
#pragma unroll
    for (int i = 0; i < 4; i++) {
      const int tau = t + i * 256;         // 1024 tasks
      const int k2 = tau >> 5, dq = tau & 31;
      vreg[i][0] = *(const uint2*)&Vp[(size_t)(kc0 * 64 + 2 * k2) * HDIM + dq * 4];
      vreg[i][1] = *(const uint2*)&Vp[(size_t)(kc0 * 64 + 2 * k2 + 1) * HDIM + dq * 4];
    }
  };

  loadKV(0);

  const int nch = qb * 2 + 2;
  for (int kc = 0; kc < nch; kc++) {
    __syncthreads();                       // all waves done reading prev LDS tiles
    // ---- commit staged K regs: row-major, 16B units ----
#pragma unroll
    for (int i = 0; i < 4; i++) {
      const int u = t + i * 256;
      const int r = u >> 4, c = (u & 15) * 8;
      *(uint4*)&Ks[r * 136 + c] = kreg[i];
    }
    // ---- commit staged V regs transposed: u32 key-pair packing + XOR swizzle ----
#pragma unroll
    for (int i = 0; i < 4; i++) {
      const int tau = t + i * 256;
      const int k2 = tau >> 5, dq = tau & 31;
      const uint2 e0 = vreg[i][0];
      const uint2 e1 = vreg[i][1];
      u32 wj[4];
      wj[0] = (e0.x & 0xFFFFu) | (e1.x << 16);
      wj[1] = (e0.x >> 16)     | (e1.x & 0xFFFF0000u);
      wj[2] = (e0.y & 0xFFFFu) | (e1.y << 16);
      wj[3] = (e0.y >> 16)     | (e1.y & 0xFFFF0000u);
      const int g = k2 >> 2;
#pragma unroll
      for (int j = 0; j < 4; j++) {
        const int d = dq * 4 + j;
        const int gs = g ^ ((d >> 3) & 7);
        Vt32[d * 36 + gs * 4 + (k2 & 3)] = wj[j];
      }
    }
    // ---- prefetch next chunk into regs; latency hides under compute below ----
    if (kc + 1 < nch) loadKV(kc + 1);
    __syncthreads();

    if (kc * 64 <= mw + 31) {   // wave has at least one unmasked key this chunk
      const bool fullch = (kc * 64 + 63 <= mw);  // wave-uniform: no masking needed
      // ---- S = QK^T ----
      f32x4 sacc[2][4] = {};
#pragma unroll
      for (int ct = 0; ct < 4; ct++) {
#pragma unroll
        for (int kk = 0; kk < 4; kk++) {
          const bf16x8 kb = *(const bf16x8*)&Ks[(ct * 16 + l15) * 136 + kk * 32 + q4 * 8];
          sacc[0][ct] = __builtin_amdgcn_mfma_f32_16x16x32_bf16(qf[0][kk], kb, sacc[0][ct], 0, 0, 0);
          sacc[1][ct] = __builtin_amdgcn_mfma_f32_16x16x32_bf16(qf[1][kk], kb, sacc[1][ct], 0, 0, 0);
        }
      }
      // ---- online softmax (row max replicated across each 16-lane quad;
      //      l kept as per-lane partial, reduced in epilogue) ----
#pragma unroll
      for (int rt = 0; rt < 2; rt++) {
        float alpha[4];
        float pv[4][4];  // [ct][rr]
#pragma unroll
        for (int rr = 0; rr < 4; rr++) {
          const int mm = mw + rt * 16 + q4 * 4 + rr;
          float sv[4];
          float vmax = -1e30f;
#pragma unroll
          for (int ct = 0; ct < 4; ct++) {
            float s = sacc[rt][ct][rr] * scale;
            if (!fullch) {
              const int key = kc * 64 + ct * 16 + l15;
              s = (key <= mm) ? s : -1e30f;
            }
            sv[ct] = s;
            vmax = fmaxf(vmax, s);
          }
          vmax = fmaxf(vmax, __shfl_xor(vmax, 1));
          vmax = fmaxf(vmax, __shfl_xor(vmax, 2));
          vmax = fmaxf(vmax, __shfl_xor(vmax, 4));
          vmax = fmaxf(vmax, __shfl_xor(vmax, 8));
          const float nm = fmaxf(mrow[rt][rr], vmax);
          float psum = 0.f;
#pragma unroll
          for (int ct = 0; ct < 4; ct++) {
            const float p = __expf(sv[ct] - nm);   // masked lanes underflow to 0
            pv[ct][rr] = p;
            psum += p;
          }
          const float al = __expf(mrow[rt][rr] - nm);
          alpha[rr] = al;
          mrow[rt][rr] = nm;
          lrow[rt][rr] = lrow[rt][rr] * al + psum;  // per-lane partial sum
        }
#pragma unroll
        for (int dt = 0; dt < 8; dt++)
#pragma unroll
          for (int rr = 0; rr < 4; rr++) oacc[rt][dt][rr] *= alpha[rr];
        // P -> per-wave LDS (row-major), scattered u16 writes
#pragma unroll
        for (int ct = 0; ct < 4; ct++)
#pragma unroll
          for (int rr = 0; rr < 4; rr++)
            Pw[(rt * 16 + q4 * 4 + rr) * 72 + ct * 16 + l15] = f2b(pv[ct][rr]);
      }
      // ---- O += P V ----
#pragma unroll
      for (int kk2 = 0; kk2 < 2; kk2++) {
        bf16x8 pa[2];
        pa[0] = *(const bf16x8*)&Pw[(l15) * 72 + kk2 * 32 + q4 * 8];
        pa[1] = *(const bf16x8*)&Pw[(16 + l15) * 72 + kk2 * 32 + q4 * 8];
#pragma unroll
        for (int dt = 0; dt < 8; dt++) {
          const int d = dt * 16 + l15;
          const int gs = (kk2 * 4 + q4) ^ ((d >> 3) & 7);
          const bf16x8 vb = *(const bf16x8*)&Vt32[d * 36 + gs * 4];
          oacc[0][dt] = __builtin_amdgcn_mfma_f32_16x16x32_bf16(pa[0], vb, oacc[0][dt], 0, 0, 0);
          oacc[1][dt] = __builtin_amdgcn_mfma_f32_16x16x32_bf16(pa[1], vb, oacc[1][dt], 0, 0, 0);
        }
      }
    }
  }

  // ---- epilogue: reduce per-lane l partials across the 16-lane quad, then
  //      O / l -> attn buffer [b][s][h*128+d] ----
#pragma unroll
  for (int rt = 0; rt < 2; rt++)
#pragma unroll
    for (int rr = 0; rr < 4; rr++) {
      float ls = lrow[rt][rr];
      ls += __shfl_xor(ls, 1);
      ls += __shfl_xor(ls, 2);
      ls += __shfl_xor(ls, 4);
      ls += __shfl_xor(ls, 8);
      const float inv = 1.0f / ls;
      const int mm = mw + rt * 16 + q4 * 4 + rr;
      u16* op = &out[((size_t)(b * SEQ + mm)) * DMODEL + h * HDIM + l15];
#pragma unroll
      for (int dt = 0; dt < 8; dt++)
        op[dt * 16] = f2b(oacc[rt][dt][rr] * inv);
    }
}

// ---------------------------------------------------------------------------
extern "C" void kernel_launch(void* const* d_in, const int* in_sizes, int n_in,
                              void* d_out, int out_size, void* d_ws, size_t ws_size,
                              hipStream_t stream) {
  const float* x     = (const float*)d_in[0];
  const float* w_qkv = (const float*)d_in[1];
  const float* b_qkv = (const float*)d_in[2];
  const float* w_o   = (const float*)d_in[3];
  const float* b_o   = (const float*)d_in[4];
  float* out = (float*)d_out;

  u16* q    = (u16*)d_ws;
  u16* k    = q + (size_t)BATCH * NHEADS * SEQ * HDIM;
  u16* v    = k + (size_t)BATCH * NKV * SEQ * HDIM;
  u16* attn = v + (size_t)BATCH * NKV * SEQ * HDIM;

  const dim3 blk(256);

  gemm_bt<0, float, float><<<dim3(QKV_DIM / 128, (BATCH * SEQ) / 128), blk, 0, stream>>>(
      x, w_qkv, b_qkv, nullptr, q, k, v, DMODEL, QKV_DIM);

  const int qrows = BATCH * NHEADS * SEQ;
  const int totrows = qrows + BATCH * NKV * SEQ;
  rope_kernel<<<dim3((totrows * 64) / 256), blk, 0, stream>>>(q, k, qrows, totrows);

  attn_mfma<<<dim3(SEQ / 128, NHEADS, BATCH), blk, 0, stream>>>(q, k, v, attn);

  gemm_bt<1, u16, float><<<dim3(DMODEL / 128, (BATCH * SEQ) / 128), blk, 0, stream>>>(
      attn, w_o, b_o, out, nullptr, nullptr, nullptr, DMODEL, DMODEL);
}

// Round 3
// 1491.152 us; speedup vs baseline: 1.1175x; 1.1175x over previous
//
#include <hip/hip_runtime.h>

typedef unsigned short u16;
typedef unsigned int   u32;

#define BATCH   2
#define SEQ     2048
#define DMODEL  4096
#define NHEADS  32
#define NKV     8
#define HDIM    128
#define QKV_DIM 6144

typedef __bf16 bf16x8 __attribute__((ext_vector_type(8)));
typedef float  f32x4  __attribute__((ext_vector_type(4)));

__device__ __forceinline__ float b2f(u16 u) {
  u32 x = ((u32)u) << 16;
  return __builtin_bit_cast(float, x);
}
__device__ __forceinline__ u16 f2b(float f) {
  u32 x = __builtin_bit_cast(u32, f);
  x = (x + 0x7FFFu + ((x >> 16) & 1u)) >> 16;  // RNE
  return (u16)x;
}
__device__ __forceinline__ float b2f_lo(u32 p) { return __builtin_bit_cast(float, p << 16); }
__device__ __forceinline__ float b2f_hi(u32 p) { return __builtin_bit_cast(float, p & 0xFFFF0000u); }

__device__ __forceinline__ u32 pk(float a, float b) {
  return (u32)f2b(a) | ((u32)f2b(b) << 16);
}

// stage 16 contiguous elements (converting to bf16 if fp32) into LDS
__device__ __forceinline__ void stage16(const float* __restrict__ g, u16* __restrict__ lds) {
  const float4* p = (const float4*)g;
  float4 a = p[0], b = p[1], c = p[2], d = p[3];
  uint4 r0, r1;
  r0.x = pk(a.x, a.y); r0.y = pk(a.z, a.w); r0.z = pk(b.x, b.y); r0.w = pk(b.z, b.w);
  r1.x = pk(c.x, c.y); r1.y = pk(c.z, c.w); r1.z = pk(d.x, d.y); r1.w = pk(d.z, d.w);
  ((uint4*)lds)[0] = r0;
  ((uint4*)lds)[1] = r1;
}
__device__ __forceinline__ void stage16(const u16* __restrict__ g, u16* __restrict__ lds) {
  const uint4* p = (const uint4*)g;
  ((uint4*)lds)[0] = p[0];
  ((uint4*)lds)[1] = p[1];
}

// ---------------------------------------------------------------------------
// GEMM: C[m][n] = sum_k A[m][k] * W[n][k] + bias[n]   (B^T-input form)
// 128x128 tile, 4 waves, BK=32, mfma_f32_16x16x32_bf16, fp32 accumulate.
// MODE 0: scatter epilogue into bf16 Q/K/V [b,h,s,d]; Q pre-scaled by 1/sqrt(d).
// MODE 1: fp32 C + bias.
// ---------------------------------------------------------------------------
template <int MODE, typename TA, typename TB>
__global__ __launch_bounds__(256) void gemm_bt(const TA* __restrict__ A,
                                               const TB* __restrict__ Bw,
                                               const float* __restrict__ bias,
                                               float* __restrict__ outf,
                                               u16* __restrict__ oq,
                                               u16* __restrict__ ok,
                                               u16* __restrict__ ov,
                                               int K, int N) {
  __shared__ u16 As[128 * 32];
  __shared__ u16 Bs[128 * 32];
  const int t    = threadIdx.x;
  const int lane = t & 63;
  const int wv   = t >> 6;
  const int wr   = wv >> 1, wc = wv & 1;
  const int m0   = blockIdx.y * 128, n0 = blockIdx.x * 128;

  f32x4 acc[4][4] = {};

  const int sr = t >> 1, sc = (t & 1) * 16;
  const TA* gA = A  + (size_t)(m0 + sr) * K + sc;
  const TB* gB = Bw + (size_t)(n0 + sr) * K + sc;
  u16* lA = &As[sr * 32 + sc];
  u16* lB = &Bs[sr * 32 + sc];

  const int kq   = (lane >> 4) * 8;
  const int arow = (wr * 64 + (lane & 15)) * 32 + kq;
  const int brow = (wc * 64 + (lane & 15)) * 32 + kq;

  for (int k0 = 0; k0 < K; k0 += 32) {
    __syncthreads();
    stage16(gA + k0, lA);
    stage16(gB + k0, lB);
    __syncthreads();

    bf16x8 af[4], bfr[4];
#pragma unroll
    for (int i = 0; i < 4; i++) af[i] = *(const bf16x8*)&As[arow + i * 512];
#pragma unroll
    for (int j = 0; j < 4; j++) bfr[j] = *(const bf16x8*)&Bs[brow + j * 512];
#pragma unroll
    for (int i = 0; i < 4; i++)
#pragma unroll
      for (int j = 0; j < 4; j++)
        acc[i][j] = __builtin_amdgcn_mfma_f32_16x16x32_bf16(af[i], bfr[j], acc[i][j], 0, 0, 0);
  }

  const int col = lane & 15, quad = lane >> 4;
#pragma unroll
  for (int j = 0; j < 4; j++) {
    const int gn = n0 + wc * 64 + j * 16 + col;
    const float bv = bias[gn];
#pragma unroll
    for (int i = 0; i < 4; i++) {
      const int gmb = m0 + wr * 64 + i * 16 + quad * 4;
#pragma unroll
      for (int rr = 0; rr < 4; rr++) {
        float val = acc[i][j][rr] + bv;
        const int gm = gmb + rr;
        if (MODE == 1) {
          outf[(size_t)gm * N + gn] = val;
        } else {
          const int b = gm >> 11, s = gm & (SEQ - 1);
          const int d = gn & (HDIM - 1);
          if (gn < 4096) {
            // fold attention scale 1/sqrt(128) into Q (commutes with RoPE)
            val *= 0.08838834764831845f;
            const int hh = gn >> 7;
            oq[((size_t)(b * NHEADS + hh) * SEQ + s) * HDIM + d] = f2b(val);
          } else if (gn < 5120) {
            const int hh = (gn - 4096) >> 7;
            ok[((size_t)(b * NKV + hh) * SEQ + s) * HDIM + d] = f2b(val);
          } else {
            const int hh = (gn - 5120) >> 7;
            ov[((size_t)(b * NKV + hh) * SEQ + s) * HDIM + d] = f2b(val);
          }
        }
      }
    }
  }
}

// ---------------------------------------------------------------------------
// RoPE in place on bf16 Q and K; cos/sin in fp32.
// ---------------------------------------------------------------------------
__global__ __launch_bounds__(256) void rope_kernel(u16* __restrict__ q, u16* __restrict__ kk,
                                                   int qrows, int totrows) {
  const int idx = blockIdx.x * 256 + threadIdx.x;
  const int row = idx >> 6;
  const int i   = idx & 63;
  if (row >= totrows) return;
  u16* base;
  int r;
  if (row < qrows) { base = q  + (size_t)row * HDIM;           r = row; }
  else             { base = kk + (size_t)(row - qrows) * HDIM; r = row - qrows; }
  const int s = r & (SEQ - 1);
  const float l2theta = 13.287712379549449f;  // log2(10000)
  const float inv = exp2f(-((float)(2 * i) * (1.0f / 128.0f)) * l2theta);
  const float ang = (float)s * inv;
  const float c  = cosf(ang);
  const float sn = sinf(ang);
  const u32 xv = *(const u32*)&base[2 * i];
  const float xr = b2f_lo(xv), xi = b2f_hi(xv);
  *(u32*)&base[2 * i] = pk(xr * c - xi * sn, xr * sn + xi * c);
}

// ---------------------------------------------------------------------------
// MFMA flash attention (causal, GQA group=4), SWAPPED-QK^T softmax.
// Block: 128 q-rows, 4 waves x 32 rows (2 row-tiles of 16). K-chunk = 64 keys.
//  * S^T = mfma(K_frag, Q_frag): lane (q4,l15) holds S[key=ct*16+q4*4+rr][q=l15]
//    -> row stats are per-lane: in-lane max tree + 2 shfl_xor (vs 8 shfl/row).
//  * l is a per-lane partial (this lane's 16 keys), reduced once in epilogue.
//  * alpha transposed to PV layout via 4 shfl per row-tile.
//  * P packed to u32 pairs -> 4x 8B LDS writes per row-tile (row stride 36 u32
//    = 144B; writes span u32 0..31 of each row).   [R2 bug: stride was 20]
//  * schedule: [stageK; issue V loads; bar; QK^T+softmax+P; V pack/write; bar;
//    PV]. V latency hides under softmax; next K-stage overlaps prev PV.
// ---------------------------------------------------------------------------
__global__ __launch_bounds__(256, 3) void attn_mfma(const u16* __restrict__ q,
                                                    const u16* __restrict__ k,
                                                    const u16* __restrict__ v,
                                                    u16* __restrict__ out) {
  __shared__ u16 Ks[64 * 136];       // [key][d], stride 136 u16 (272B)
  __shared__ u16 VtBuf[128 * 72];    // [d][key-swizzled], stride 72 u16 (144B)
  __shared__ u32 Ps32[4 * 32 * 36];  // per wave: [row][key-pair], stride 36 u32
  u32* Vt32 = (u32*)VtBuf;           // row stride 36 u32

  const int t    = threadIdx.x;
  const int lane = t & 63;
  const int w    = t >> 6;
  const int q4   = lane >> 4, l15 = lane & 15;
  const int qb   = 15 - (int)blockIdx.x;   // heavy blocks first
  const int h = blockIdx.y, b = blockIdx.z;
  const int m0 = qb * 128;
  const int mw = m0 + w * 32;              // wave's first q-row
  const int kvh = h >> 2;
  const u16* Qp = q + (size_t)(b * NHEADS + h) * SEQ * HDIM;
  const u16* Kp = k + (size_t)(b * NKV + kvh) * SEQ * HDIM;
  const u16* Vp = v + (size_t)(b * NKV + kvh) * SEQ * HDIM;

  // Q fragments (held in registers; Q already scaled by 1/sqrt(d))
  bf16x8 qf[2][4];
#pragma unroll
  for (int rt = 0; rt < 2; rt++)
#pragma unroll
    for (int kk = 0; kk < 4; kk++)
      qf[rt][kk] = *(const bf16x8*)&Qp[(size_t)(mw + rt * 16 + l15) * HDIM + kk * 32 + q4 * 8];

  f32x4 oacc[2][8] = {};
  float mrow[2], lrow[2];
  mrow[0] = mrow[1] = -1e30f;
  lrow[0] = lrow[1] = 0.f;

  u32* Pw32 = &Ps32[w * 32 * 36];

  const int nch = qb * 2 + 2;
  for (int kc = 0; kc < nch; kc++) {
    // ---- stage K: row-major, vector 16B units, coalesced (overlaps prev PV) ----
#pragma unroll
    for (int i = 0; i < 4; i++) {
      const int u = t + i * 256;           // 1024 units of 16B
      const int r = u >> 4, c = (u & 15) * 8;
      *(uint4*)&Ks[r * 136 + c] = *(const uint4*)&Kp[(size_t)(kc * 64 + r) * HDIM + c];
    }
    // ---- issue V loads now; consumed after softmax (latency hides under it) ----
    uint2 e0[4], e1[4];
#pragma unroll
    for (int i = 0; i < 4; i++) {
      const int tau = t + i * 256;         // 1024 tasks
      const int k2 = tau >> 5, dq = tau & 31;
      e0[i] = *(const uint2*)&Vp[(size_t)(kc * 64 + 2 * k2) * HDIM + dq * 4];
      e1[i] = *(const uint2*)&Vp[(size_t)(kc * 64 + 2 * k2 + 1) * HDIM + dq * 4];
    }
    __syncthreads();   // A: Ks published; prev-chunk Vt readers all done

    const bool part = (kc * 64 <= mw + 31);
    if (part) {
      const bool fullch = (kc * 64 + 63 <= mw);  // wave-uniform: no masking needed
      // ---- S^T = K Q^T (swapped operands; same LDS reads as before) ----
      f32x4 sacc[2][4] = {};
      __builtin_amdgcn_s_setprio(1);
#pragma unroll
      for (int ct = 0; ct < 4; ct++) {
#pragma unroll
        for (int kk = 0; kk < 4; kk++) {
          const bf16x8 kb = *(const bf16x8*)&Ks[(ct * 16 + l15) * 136 + kk * 32 + q4 * 8];
          sacc[0][ct] = __builtin_amdgcn_mfma_f32_16x16x32_bf16(kb, qf[0][kk], sacc[0][ct], 0, 0, 0);
          sacc[1][ct] = __builtin_amdgcn_mfma_f32_16x16x32_bf16(kb, qf[1][kk], sacc[1][ct], 0, 0, 0);
        }
      }
      __builtin_amdgcn_s_setprio(0);
      // ---- softmax: lane owns 16 keys of q-row (rt*16+l15) ----
#pragma unroll
      for (int rt = 0; rt < 2; rt++) {
        float p[4][4];
        float cm[4];
        const int mm = mw + rt * 16 + l15;
#pragma unroll
        for (int ct = 0; ct < 4; ct++) {
#pragma unroll
          for (int rr = 0; rr < 4; rr++) {
            float s = sacc[rt][ct][rr];
            if (!fullch) {
              const int key = kc * 64 + ct * 16 + q4 * 4 + rr;
              s = (key <= mm) ? s : -1e30f;
            }
            p[ct][rr] = s;
          }
          cm[ct] = fmaxf(fmaxf(p[ct][0], p[ct][1]), fmaxf(p[ct][2], p[ct][3]));
        }
        float vmax = fmaxf(fmaxf(cm[0], cm[1]), fmaxf(cm[2], cm[3]));
        vmax = fmaxf(vmax, __shfl_xor(vmax, 16));
        vmax = fmaxf(vmax, __shfl_xor(vmax, 32));
        const float nm = fmaxf(mrow[rt], vmax);
        const float alpha = __expf(mrow[rt] - nm);
        mrow[rt] = nm;
        float cs[4];
#pragma unroll
        for (int ct = 0; ct < 4; ct++) {
#pragma unroll
          for (int rr = 0; rr < 4; rr++) p[ct][rr] = __expf(p[ct][rr] - nm);
          cs[ct] = (p[ct][0] + p[ct][1]) + (p[ct][2] + p[ct][3]);
        }
        lrow[rt] = lrow[rt] * alpha + ((cs[0] + cs[1]) + (cs[2] + cs[3]));
        // P -> LDS, packed u32 key-pairs (8B per ct); row spans u32 0..31
#pragma unroll
        for (int ct = 0; ct < 4; ct++) {
          uint2 w2;
          w2.x = pk(p[ct][0], p[ct][1]);
          w2.y = pk(p[ct][2], p[ct][3]);
          *(uint2*)&Pw32[(rt * 16 + l15) * 36 + ct * 8 + q4 * 2] = w2;
        }
        // alpha -> PV layout (row q4*4+rr) and rescale O
        float alT[4];
#pragma unroll
        for (int rr = 0; rr < 4; rr++) alT[rr] = __shfl(alpha, q4 * 4 + rr, 64);
#pragma unroll
        for (int dt = 0; dt < 8; dt++)
#pragma unroll
          for (int rr = 0; rr < 4; rr++) oacc[rt][dt][rr] *= alT[rr];
      }
    }
    // ---- commit V transposed: u32 key-pair packing + XOR group swizzle ----
#pragma unroll
    for (int i = 0; i < 4; i++) {
      const int tau = t + i * 256;
      const int k2 = tau >> 5, dq = tau & 31;
      u32 wj[4];
      wj[0] = (e0[i].x & 0xFFFFu) | (e1[i].x << 16);
      wj[1] = (e0[i].x >> 16)     | (e1[i].x & 0xFFFF0000u);
      wj[2] = (e0[i].y & 0xFFFFu) | (e1[i].y << 16);
      wj[3] = (e0[i].y >> 16)     | (e1[i].y & 0xFFFF0000u);
      const int g = k2 >> 2;
#pragma unroll
      for (int j = 0; j < 4; j++) {
        const int d = dq * 4 + j;
        const int gs = g ^ ((d >> 3) & 7);
        Vt32[d * 36 + gs * 4 + (k2 & 3)] = wj[j];
      }
    }
    __syncthreads();   // B: Vt published

    if (part) {
      // ---- O += P V ----
      __builtin_amdgcn_s_setprio(1);
#pragma unroll
      for (int kk2 = 0; kk2 < 2; kk2++) {
        bf16x8 pa[2];
        pa[0] = *(const bf16x8*)&Pw32[(l15) * 36 + kk2 * 16 + q4 * 4];
        pa[1] = *(const bf16x8*)&Pw32[(16 + l15) * 36 + kk2 * 16 + q4 * 4];
#pragma unroll
        for (int dt = 0; dt < 8; dt++) {
          const int d = dt * 16 + l15;
          const int gs = (kk2 * 4 + q4) ^ ((d >> 3) & 7);
          const bf16x8 vb = *(const bf16x8*)&Vt32[d * 36 + gs * 4];
          oacc[0][dt] = __builtin_amdgcn_mfma_f32_16x16x32_bf16(pa[0], vb, oacc[0][dt], 0, 0, 0);
          oacc[1][dt] = __builtin_amdgcn_mfma_f32_16x16x32_bf16(pa[1], vb, oacc[1][dt], 0, 0, 0);
        }
      }
      __builtin_amdgcn_s_setprio(0);
    }
  }

  // ---- epilogue: reduce l partials (4 q4-lanes), transpose to PV layout,
  //      O / l -> attn buffer [b][s][h*128+d] ----
#pragma unroll
  for (int rt = 0; rt < 2; rt++) {
    float ls = lrow[rt];
    ls += __shfl_xor(ls, 16);
    ls += __shfl_xor(ls, 32);
#pragma unroll
    for (int rr = 0; rr < 4; rr++) {
      const float lt = __shfl(ls, q4 * 4 + rr, 64);
      const float inv = 1.0f / lt;
      const int mm = mw + rt * 16 + q4 * 4 + rr;
      u16* op = &out[((size_t)(b * SEQ + mm)) * DMODEL + h * HDIM + l15];
#pragma unroll
      for (int dt = 0; dt < 8; dt++)
        op[dt * 16] = f2b(oacc[rt][dt][rr] * inv);
    }
  }
}

// ---------------------------------------------------------------------------
extern "C" void kernel_launch(void* const* d_in, const int* in_sizes, int n_in,
                              void* d_out, int out_size, void* d_ws, size_t ws_size,
                              hipStream_t stream) {
  const float* x     = (const float*)d_in[0];
  const float* w_qkv = (const float*)d_in[1];
  const float* b_qkv = (const float*)d_in[2];
  const float* w_o   = (const float*)d_in[3];
  const float* b_o   = (const float*)d_in[4];
  float* out = (float*)d_out;

  u16* q    = (u16*)d_ws;
  u16* k    = q + (size_t)BATCH * NHEADS * SEQ * HDIM;
  u16* v    = k + (size_t)BATCH * NKV * SEQ * HDIM;
  u16* attn = v + (size_t)BATCH * NKV * SEQ * HDIM;

  const dim3 blk(256);

  gemm_bt<0, float, float><<<dim3(QKV_DIM / 128, (BATCH * SEQ) / 128), blk, 0, stream>>>(
      x, w_qkv, b_qkv, nullptr, q, k, v, DMODEL, QKV_DIM);

  const int qrows = BATCH * NHEADS * SEQ;
  const int totrows = qrows + BATCH * NKV * SEQ;
  rope_kernel<<<dim3((totrows * 64) / 256), blk, 0, stream>>>(q, k, qrows, totrows);

  attn_mfma<<<dim3(SEQ / 128, NHEADS, BATCH), blk, 0, stream>>>(q, k, v, attn);

  gemm_bt<1, u16, float><<<dim3(DMODEL / 128, (BATCH * SEQ) / 128), blk, 0, stream>>>(
      attn, w_o, b_o, out, nullptr, nullptr, nullptr, DMODEL, DMODEL);
}

// Round 4
// 1342.742 us; speedup vs baseline: 1.2410x; 1.1105x over previous
//
#include <hip/hip_runtime.h>

typedef unsigned short u16;
typedef unsigned int   u32;

#define BATCH   2
#define SEQ     2048
#define DMODEL  4096
#define NHEADS  32
#define NKV     8
#define HDIM    128
#define QKV_DIM 6144

typedef __bf16 bf16x8 __attribute__((ext_vector_type(8)));
typedef float  f32x4  __attribute__((ext_vector_type(4)));

__device__ __forceinline__ float b2f(u16 u) {
  u32 x = ((u32)u) << 16;
  return __builtin_bit_cast(float, x);
}
__device__ __forceinline__ u16 f2b(float f) {
  u32 x = __builtin_bit_cast(u32, f);
  x = (x + 0x7FFFu + ((x >> 16) & 1u)) >> 16;  // RNE
  return (u16)x;
}
__device__ __forceinline__ float b2f_lo(u32 p) { return __builtin_bit_cast(float, p << 16); }
__device__ __forceinline__ float b2f_hi(u32 p) { return __builtin_bit_cast(float, p & 0xFFFF0000u); }

__device__ __forceinline__ u32 pk(float a, float b) {
  return (u32)f2b(a) | ((u32)f2b(b) << 16);
}

// stage 16 contiguous fp32 (converting to bf16) into LDS
__device__ __forceinline__ void stage16(const float* __restrict__ g, u16* __restrict__ lds) {
  const float4* p = (const float4*)g;
  float4 a = p[0], b = p[1], c = p[2], d = p[3];
  uint4 r0, r1;
  r0.x = pk(a.x, a.y); r0.y = pk(a.z, a.w); r0.z = pk(b.x, b.y); r0.w = pk(b.z, b.w);
  r1.x = pk(c.x, c.y); r1.y = pk(c.z, c.w); r1.z = pk(d.x, d.y); r1.w = pk(d.z, d.w);
  ((uint4*)lds)[0] = r0;
  ((uint4*)lds)[1] = r1;
}

// async 16B global -> LDS (DMA; no VGPR round-trip). Dest must be linear in
// lane order within a wave (wave-uniform base + lane*16) -- our staging is.
__device__ __forceinline__ void gload16(const u16* __restrict__ g, u16* l) {
  __builtin_amdgcn_global_load_lds(
      (const __attribute__((address_space(1))) unsigned int*)(const void*)g,
      (__attribute__((address_space(3))) unsigned int*)(void*)l,
      16, 0, 0);
}

// ---------------------------------------------------------------------------
// fp32 -> bf16 bulk convert (for weights), 8 elems/thread, vectorized.
// ---------------------------------------------------------------------------
__global__ __launch_bounds__(256) void f32_to_bf16(const float* __restrict__ in,
                                                   u16* __restrict__ out, int n8) {
  const int i = blockIdx.x * 256 + threadIdx.x;
  if (i >= n8) return;
  const float4* p = (const float4*)(in + (size_t)i * 8);
  const float4 a = p[0], b = p[1];
  uint4 r;
  r.x = pk(a.x, a.y); r.y = pk(a.z, a.w); r.z = pk(b.x, b.y); r.w = pk(b.z, b.w);
  ((uint4*)out)[i] = r;
}

// ---------------------------------------------------------------------------
// GEMM (m97 structure): C[m][n] = sum_k A[m][k] * W[n][k] + bias[n]
// 128x128 tile, 4 waves, BK=64, mfma_f32_16x16x32_bf16, fp32 accumulate.
// B (bf16 weights) staged via global_load_lds dwordx4 into linear LDS.
// A: A_BF16=1 -> global_load_lds (bf16 source); A_BF16=0 -> fp32 reg-stage+cvt.
// MODE 0: scatter epilogue into bf16 Q/K/V [b,h,s,d]; Q pre-scaled by 1/sqrt(d).
// MODE 1: fp32 C + bias.
// ---------------------------------------------------------------------------
template <int MODE, int A_BF16>
__global__ __launch_bounds__(256) void gemm_bt2(const void* __restrict__ Av,
                                                const u16* __restrict__ Bw,
                                                const float* __restrict__ bias,
                                                float* __restrict__ outf,
                                                u16* __restrict__ oq,
                                                u16* __restrict__ ok,
                                                u16* __restrict__ ov,
                                                int K, int N) {
  __shared__ u16 As[128 * 64];
  __shared__ u16 Bs[128 * 64];
  const int t    = threadIdx.x;
  const int lane = t & 63;
  const int wv   = t >> 6;
  const int wr   = wv >> 1, wc = wv & 1;
  const int m0   = blockIdx.y * 128, n0 = blockIdx.x * 128;
  const int q4   = lane >> 4, l15 = lane & 15;

  f32x4 acc[4][4] = {};

  for (int k0 = 0; k0 < K; k0 += 64) {
    __syncthreads();
    // ---- B tile: 1024 x 16B units via async DMA ----
#pragma unroll
    for (int i = 0; i < 4; i++) {
      const int u = t + i * 256;
      const int r = u >> 3, c8 = (u & 7) * 8;
      gload16(Bw + (size_t)(n0 + r) * K + k0 + c8, &Bs[u * 8]);
    }
    // ---- A tile ----
    if (A_BF16) {
      const u16* Ab = (const u16*)Av;
#pragma unroll
      for (int i = 0; i < 4; i++) {
        const int u = t + i * 256;
        const int r = u >> 3, c8 = (u & 7) * 8;
        gload16(Ab + (size_t)(m0 + r) * K + k0 + c8, &As[u * 8]);
      }
    } else {
      const float* Af = (const float*)Av;
#pragma unroll
      for (int i = 0; i < 2; i++) {
        const int u = t + i * 256;           // 512 units of 16 fp32
        const int r = u >> 2, c16 = (u & 3) * 16;
        stage16(Af + (size_t)(m0 + r) * K + k0 + c16, &As[r * 64 + c16]);
      }
    }
    __syncthreads();   // drains vmcnt(0) -> LDS data visible

    // ---- fragments + MFMA: 2 k-steps of 32 ----
#pragma unroll
    for (int kk = 0; kk < 2; kk++) {
      bf16x8 af[4], bfr[4];
#pragma unroll
      for (int i = 0; i < 4; i++)
        af[i] = *(const bf16x8*)&As[(wr * 64 + i * 16 + l15) * 64 + kk * 32 + q4 * 8];
#pragma unroll
      for (int j = 0; j < 4; j++)
        bfr[j] = *(const bf16x8*)&Bs[(wc * 64 + j * 16 + l15) * 64 + kk * 32 + q4 * 8];
#pragma unroll
      for (int i = 0; i < 4; i++)
#pragma unroll
        for (int j = 0; j < 4; j++)
          acc[i][j] = __builtin_amdgcn_mfma_f32_16x16x32_bf16(af[i], bfr[j], acc[i][j], 0, 0, 0);
    }
  }

  const int col = l15, quad = q4;
#pragma unroll
  for (int j = 0; j < 4; j++) {
    const int gn = n0 + wc * 64 + j * 16 + col;
    const float bv = bias[gn];
#pragma unroll
    for (int i = 0; i < 4; i++) {
      const int gmb = m0 + wr * 64 + i * 16 + quad * 4;
#pragma unroll
      for (int rr = 0; rr < 4; rr++) {
        float val = acc[i][j][rr] + bv;
        const int gm = gmb + rr;
        if (MODE == 1) {
          outf[(size_t)gm * N + gn] = val;
        } else {
          const int b = gm >> 11, s = gm & (SEQ - 1);
          const int d = gn & (HDIM - 1);
          if (gn < 4096) {
            // fold attention scale 1/sqrt(128) into Q (commutes with RoPE)
            val *= 0.08838834764831845f;
            const int hh = gn >> 7;
            oq[((size_t)(b * NHEADS + hh) * SEQ + s) * HDIM + d] = f2b(val);
          } else if (gn < 5120) {
            const int hh = (gn - 4096) >> 7;
            ok[((size_t)(b * NKV + hh) * SEQ + s) * HDIM + d] = f2b(val);
          } else {
            const int hh = (gn - 5120) >> 7;
            ov[((size_t)(b * NKV + hh) * SEQ + s) * HDIM + d] = f2b(val);
          }
        }
      }
    }
  }
}

// ---------------------------------------------------------------------------
// RoPE in place on bf16 Q and K; cos/sin in fp32.
// ---------------------------------------------------------------------------
__global__ __launch_bounds__(256) void rope_kernel(u16* __restrict__ q, u16* __restrict__ kk,
                                                   int qrows, int totrows) {
  const int idx = blockIdx.x * 256 + threadIdx.x;
  const int row = idx >> 6;
  const int i   = idx & 63;
  if (row >= totrows) return;
  u16* base;
  int r;
  if (row < qrows) { base = q  + (size_t)row * HDIM;           r = row; }
  else             { base = kk + (size_t)(row - qrows) * HDIM; r = row - qrows; }
  const int s = r & (SEQ - 1);
  const float l2theta = 13.287712379549449f;  // log2(10000)
  const float inv = exp2f(-((float)(2 * i) * (1.0f / 128.0f)) * l2theta);
  const float ang = (float)s * inv;
  const float c  = cosf(ang);
  const float sn = sinf(ang);
  const u32 xv = *(const u32*)&base[2 * i];
  const float xr = b2f_lo(xv), xi = b2f_hi(xv);
  *(u32*)&base[2 * i] = pk(xr * c - xi * sn, xr * sn + xi * c);
}

// ---------------------------------------------------------------------------
// MFMA flash attention (causal, GQA group=4), SWAPPED-QK^T softmax.
// (unchanged from Round 3 -- 540 us, passes; spill tuning deferred)
// ---------------------------------------------------------------------------
__global__ __launch_bounds__(256, 3) void attn_mfma(const u16* __restrict__ q,
                                                    const u16* __restrict__ k,
                                                    const u16* __restrict__ v,
                                                    u16* __restrict__ out) {
  __shared__ u16 Ks[64 * 136];       // [key][d], stride 136 u16 (272B)
  __shared__ u16 VtBuf[128 * 72];    // [d][key-swizzled], stride 72 u16 (144B)
  __shared__ u32 Ps32[4 * 32 * 36];  // per wave: [row][key-pair], stride 36 u32
  u32* Vt32 = (u32*)VtBuf;           // row stride 36 u32

  const int t    = threadIdx.x;
  const int lane = t & 63;
  const int w    = t >> 6;
  const int q4   = lane >> 4, l15 = lane & 15;
  const int qb   = 15 - (int)blockIdx.x;   // heavy blocks first
  const int h = blockIdx.y, b = blockIdx.z;
  const int m0 = qb * 128;
  const int mw = m0 + w * 32;              // wave's first q-row
  const int kvh = h >> 2;
  const u16* Qp = q + (size_t)(b * NHEADS + h) * SEQ * HDIM;
  const u16* Kp = k + (size_t)(b * NKV + kvh) * SEQ * HDIM;
  const u16* Vp = v + (size_t)(b * NKV + kvh) * SEQ * HDIM;

  // Q fragments (held in registers; Q already scaled by 1/sqrt(d))
  bf16x8 qf[2][4];
#pragma unroll
  for (int rt = 0; rt < 2; rt++)
#pragma unroll
    for (int kk = 0; kk < 4; kk++)
      qf[rt][kk] = *(const bf16x8*)&Qp[(size_t)(mw + rt * 16 + l15) * HDIM + kk * 32 + q4 * 8];

  f32x4 oacc[2][8] = {};
  float mrow[2], lrow[2];
  mrow[0] = mrow[1] = -1e30f;
  lrow[0] = lrow[1] = 0.f;

  u32* Pw32 = &Ps32[w * 32 * 36];

  const int nch = qb * 2 + 2;
  for (int kc = 0; kc < nch; kc++) {
    // ---- stage K: row-major, vector 16B units, coalesced (overlaps prev PV) ----
#pragma unroll
    for (int i = 0; i < 4; i++) {
      const int u = t + i * 256;           // 1024 units of 16B
      const int r = u >> 4, c = (u & 15) * 8;
      *(uint4*)&Ks[r * 136 + c] = *(const uint4*)&Kp[(size_t)(kc * 64 + r) * HDIM + c];
    }
    // ---- issue V loads now; consumed after softmax (latency hides under it) ----
    uint2 e0[4], e1[4];
#pragma unroll
    for (int i = 0; i < 4; i++) {
      const int tau = t + i * 256;         // 1024 tasks
      const int k2 = tau >> 5, dq = tau & 31;
      e0[i] = *(const uint2*)&Vp[(size_t)(kc * 64 + 2 * k2) * HDIM + dq * 4];
      e1[i] = *(const uint2*)&Vp[(size_t)(kc * 64 + 2 * k2 + 1) * HDIM + dq * 4];
    }
    __syncthreads();   // A: Ks published; prev-chunk Vt readers all done

    const bool part = (kc * 64 <= mw + 31);
    if (part) {
      const bool fullch = (kc * 64 + 63 <= mw);  // wave-uniform: no masking needed
      // ---- S^T = K Q^T (swapped operands) ----
      f32x4 sacc[2][4] = {};
      __builtin_amdgcn_s_setprio(1);
#pragma unroll
      for (int ct = 0; ct < 4; ct++) {
#pragma unroll
        for (int kk = 0; kk < 4; kk++) {
          const bf16x8 kb = *(const bf16x8*)&Ks[(ct * 16 + l15) * 136 + kk * 32 + q4 * 8];
          sacc[0][ct] = __builtin_amdgcn_mfma_f32_16x16x32_bf16(kb, qf[0][kk], sacc[0][ct], 0, 0, 0);
          sacc[1][ct] = __builtin_amdgcn_mfma_f32_16x16x32_bf16(kb, qf[1][kk], sacc[1][ct], 0, 0, 0);
        }
      }
      __builtin_amdgcn_s_setprio(0);
      // ---- softmax: lane owns 16 keys of q-row (rt*16+l15) ----
#pragma unroll
      for (int rt = 0; rt < 2; rt++) {
        float p[4][4];
        float cm[4];
        const int mm = mw + rt * 16 + l15;
#pragma unroll
        for (int ct = 0; ct < 4; ct++) {
#pragma unroll
          for (int rr = 0; rr < 4; rr++) {
            float s = sacc[rt][ct][rr];
            if (!fullch) {
              const int key = kc * 64 + ct * 16 + q4 * 4 + rr;
              s = (key <= mm) ? s : -1e30f;
            }
            p[ct][rr] = s;
          }
          cm[ct] = fmaxf(fmaxf(p[ct][0], p[ct][1]), fmaxf(p[ct][2], p[ct][3]));
        }
        float vmax = fmaxf(fmaxf(cm[0], cm[1]), fmaxf(cm[2], cm[3]));
        vmax = fmaxf(vmax, __shfl_xor(vmax, 16));
        vmax = fmaxf(vmax, __shfl_xor(vmax, 32));
        const float nm = fmaxf(mrow[rt], vmax);
        const float alpha = __expf(mrow[rt] - nm);
        mrow[rt] = nm;
        float cs[4];
#pragma unroll
        for (int ct = 0; ct < 4; ct++) {
#pragma unroll
          for (int rr = 0; rr < 4; rr++) p[ct][rr] = __expf(p[ct][rr] - nm);
          cs[ct] = (p[ct][0] + p[ct][1]) + (p[ct][2] + p[ct][3]);
        }
        lrow[rt] = lrow[rt] * alpha + ((cs[0] + cs[1]) + (cs[2] + cs[3]));
        // P -> LDS, packed u32 key-pairs (8B per ct); row spans u32 0..31
#pragma unroll
        for (int ct = 0; ct < 4; ct++) {
          uint2 w2;
          w2.x = pk(p[ct][0], p[ct][1]);
          w2.y = pk(p[ct][2], p[ct][3]);
          *(uint2*)&Pw32[(rt * 16 + l15) * 36 + ct * 8 + q4 * 2] = w2;
        }
        // alpha -> PV layout (row q4*4+rr) and rescale O
        float alT[4];
#pragma unroll
        for (int rr = 0; rr < 4; rr++) alT[rr] = __shfl(alpha, q4 * 4 + rr, 64);
#pragma unroll
        for (int dt = 0; dt < 8; dt++)
#pragma unroll
          for (int rr = 0; rr < 4; rr++) oacc[rt][dt][rr] *= alT[rr];
      }
    }
    // ---- commit V transposed: u32 key-pair packing + XOR group swizzle ----
#pragma unroll
    for (int i = 0; i < 4; i++) {
      const int tau = t + i * 256;
      const int k2 = tau >> 5, dq = tau & 31;
      u32 wj[4];
      wj[0] = (e0[i].x & 0xFFFFu) | (e1[i].x << 16);
      wj[1] = (e0[i].x >> 16)     | (e1[i].x & 0xFFFF0000u);
      wj[2] = (e0[i].y & 0xFFFFu) | (e1[i].y << 16);
      wj[3] = (e0[i].y >> 16)     | (e1[i].y & 0xFFFF0000u);
      const int g = k2 >> 2;
#pragma unroll
      for (int j = 0; j < 4; j++) {
        const int d = dq * 4 + j;
        const int gs = g ^ ((d >> 3) & 7);
        Vt32[d * 36 + gs * 4 + (k2 & 3)] = wj[j];
      }
    }
    __syncthreads();   // B: Vt published

    if (part) {
      // ---- O += P V ----
      __builtin_amdgcn_s_setprio(1);
#pragma unroll
      for (int kk2 = 0; kk2 < 2; kk2++) {
        bf16x8 pa[2];
        pa[0] = *(const bf16x8*)&Pw32[(l15) * 36 + kk2 * 16 + q4 * 4];
        pa[1] = *(const bf16x8*)&Pw32[(16 + l15) * 36 + kk2 * 16 + q4 * 4];
#pragma unroll
        for (int dt = 0; dt < 8; dt++) {
          const int d = dt * 16 + l15;
          const int gs = (kk2 * 4 + q4) ^ ((d >> 3) & 7);
          const bf16x8 vb = *(const bf16x8*)&Vt32[d * 36 + gs * 4];
          oacc[0][dt] = __builtin_amdgcn_mfma_f32_16x16x32_bf16(pa[0], vb, oacc[0][dt], 0, 0, 0);
          oacc[1][dt] = __builtin_amdgcn_mfma_f32_16x16x32_bf16(pa[1], vb, oacc[1][dt], 0, 0, 0);
        }
      }
      __builtin_amdgcn_s_setprio(0);
    }
  }

  // ---- epilogue: reduce l partials (4 q4-lanes), transpose to PV layout,
  //      O / l -> attn buffer [b][s][h*128+d] ----
#pragma unroll
  for (int rt = 0; rt < 2; rt++) {
    float ls = lrow[rt];
    ls += __shfl_xor(ls, 16);
    ls += __shfl_xor(ls, 32);
#pragma unroll
    for (int rr = 0; rr < 4; rr++) {
      const float lt = __shfl(ls, q4 * 4 + rr, 64);
      const float inv = 1.0f / lt;
      const int mm = mw + rt * 16 + q4 * 4 + rr;
      u16* op = &out[((size_t)(b * SEQ + mm)) * DMODEL + h * HDIM + l15];
#pragma unroll
      for (int dt = 0; dt < 8; dt++)
        op[dt * 16] = f2b(oacc[rt][dt][rr] * inv);
    }
  }
}

// ---------------------------------------------------------------------------
extern "C" void kernel_launch(void* const* d_in, const int* in_sizes, int n_in,
                              void* d_out, int out_size, void* d_ws, size_t ws_size,
                              hipStream_t stream) {
  const float* x     = (const float*)d_in[0];
  const float* w_qkv = (const float*)d_in[1];
  const float* b_qkv = (const float*)d_in[2];
  const float* w_o   = (const float*)d_in[3];
  const float* b_o   = (const float*)d_in[4];
  float* out = (float*)d_out;

  const size_t QN = (size_t)BATCH * NHEADS * SEQ * HDIM;   // 16.78M u16
  const size_t KN = (size_t)BATCH * NKV * SEQ * HDIM;      //  4.19M u16

  u16* q    = (u16*)d_ws;
  u16* k    = q + QN;
  u16* v    = k + KN;
  u16* attn = v + KN;
  u16* wb   = attn + QN;   // bf16 weight buffer: w_qkv (25.17M u16), reused for w_o

  const dim3 blk(256);

  // ---- convert w_qkv -> bf16 ----
  const int n8_qkv = QKV_DIM * DMODEL / 8;
  f32_to_bf16<<<dim3(n8_qkv / 256), blk, 0, stream>>>(w_qkv, wb, n8_qkv);

  // ---- QKV GEMM: A = x (fp32, reg-staged), B = wb (bf16, DMA-staged) ----
  gemm_bt2<0, 0><<<dim3(QKV_DIM / 128, (BATCH * SEQ) / 128), blk, 0, stream>>>(
      x, wb, b_qkv, nullptr, q, k, v, DMODEL, QKV_DIM);

  const int qrows = BATCH * NHEADS * SEQ;
  const int totrows = qrows + BATCH * NKV * SEQ;
  rope_kernel<<<dim3((totrows * 64) / 256), blk, 0, stream>>>(q, k, qrows, totrows);

  attn_mfma<<<dim3(SEQ / 128, NHEADS, BATCH), blk, 0, stream>>>(q, k, v, attn);

  // ---- convert w_o -> bf16 (reuses wb; w_qkv copy is dead now) ----
  const int n8_o = DMODEL * DMODEL / 8;
  f32_to_bf16<<<dim3(n8_o / 256), blk, 0, stream>>>(w_o, wb, n8_o);

  // ---- output GEMM: A = attn (bf16, DMA-staged), B = wb (bf16, DMA-staged) ----
  gemm_bt2<1, 1><<<dim3(DMODEL / 128, (BATCH * SEQ) / 128), blk, 0, stream>>>(
      attn, wb, b_o, out, nullptr, nullptr, nullptr, DMODEL, DMODEL);
}

// Round 5
// 1229.014 us; speedup vs baseline: 1.3559x; 1.0925x over previous
//
#include <hip/hip_runtime.h>

typedef unsigned short u16;
typedef unsigned int   u32;

#define BATCH   2
#define SEQ     2048
#define DMODEL  4096
#define NHEADS  32
#define NKV     8
#define HDIM    128
#define QKV_DIM 6144

typedef __bf16 bf16x8 __attribute__((ext_vector_type(8)));
typedef float  f32x4  __attribute__((ext_vector_type(4)));

__device__ __forceinline__ float b2f(u16 u) {
  u32 x = ((u32)u) << 16;
  return __builtin_bit_cast(float, x);
}
__device__ __forceinline__ u16 f2b(float f) {
  u32 x = __builtin_bit_cast(u32, f);
  x = (x + 0x7FFFu + ((x >> 16) & 1u)) >> 16;  // RNE
  return (u16)x;
}
__device__ __forceinline__ float b2f_lo(u32 p) { return __builtin_bit_cast(float, p << 16); }
__device__ __forceinline__ float b2f_hi(u32 p) { return __builtin_bit_cast(float, p & 0xFFFF0000u); }

__device__ __forceinline__ u32 pk(float a, float b) {
  return (u32)f2b(a) | ((u32)f2b(b) << 16);
}

// async 16B global -> LDS (DMA; no VGPR round-trip). Dest must be linear in
// lane order within a wave (wave-uniform base + lane*16) -- our staging is.
__device__ __forceinline__ void gload16(const u16* __restrict__ g, u16* l) {
  __builtin_amdgcn_global_load_lds(
      (const __attribute__((address_space(1))) unsigned int*)(const void*)g,
      (__attribute__((address_space(3))) unsigned int*)(void*)l,
      16, 0, 0);
}

// ---------------------------------------------------------------------------
// fp32 -> bf16 bulk convert, 8 elems/thread, vectorized. (weights + x)
// ---------------------------------------------------------------------------
__global__ __launch_bounds__(256) void f32_to_bf16(const float* __restrict__ in,
                                                   u16* __restrict__ out, int n8) {
  const int i = blockIdx.x * 256 + threadIdx.x;
  if (i >= n8) return;
  const float4* p = (const float4*)(in + (size_t)i * 8);
  const float4 a = p[0], b = p[1];
  uint4 r;
  r.x = pk(a.x, a.y); r.y = pk(a.z, a.w); r.z = pk(b.x, b.y); r.w = pk(b.z, b.w);
  ((uint4*)out)[i] = r;
}

// ---------------------------------------------------------------------------
// GEMM (m97 structure): C[m][n] = sum_k A[m][k] * W[n][k] + bias[n]
// 128x128 tile, 4 waves, BK=64, mfma_f32_16x16x32_bf16, fp32 accumulate.
// BOTH operands bf16, staged via global_load_lds dwordx4 into linear LDS.
// MODE 0: scatter epilogue into bf16 Q/K/V [b,h,s,d]; Q pre-scaled by 1/sqrt(d).
// MODE 1: fp32 C + bias.
// ---------------------------------------------------------------------------
template <int MODE>
__global__ __launch_bounds__(256) void gemm_bt2(const u16* __restrict__ Ab,
                                                const u16* __restrict__ Bw,
                                                const float* __restrict__ bias,
                                                float* __restrict__ outf,
                                                u16* __restrict__ oq,
                                                u16* __restrict__ ok,
                                                u16* __restrict__ ov,
                                                int K, int N) {
  __shared__ u16 As[128 * 64];
  __shared__ u16 Bs[128 * 64];
  const int t    = threadIdx.x;
  const int lane = t & 63;
  const int wv   = t >> 6;
  const int wr   = wv >> 1, wc = wv & 1;
  const int m0   = blockIdx.y * 128, n0 = blockIdx.x * 128;
  const int q4   = lane >> 4, l15 = lane & 15;

  f32x4 acc[4][4] = {};

  for (int k0 = 0; k0 < K; k0 += 64) {
    __syncthreads();
    // ---- A + B tiles: 1024 x 16B units each via async DMA ----
#pragma unroll
    for (int i = 0; i < 4; i++) {
      const int u = t + i * 256;
      const int r = u >> 3, c8 = (u & 7) * 8;
      gload16(Bw + (size_t)(n0 + r) * K + k0 + c8, &Bs[u * 8]);
    }
#pragma unroll
    for (int i = 0; i < 4; i++) {
      const int u = t + i * 256;
      const int r = u >> 3, c8 = (u & 7) * 8;
      gload16(Ab + (size_t)(m0 + r) * K + k0 + c8, &As[u * 8]);
    }
    __syncthreads();   // drains vmcnt(0) -> LDS data visible

    // ---- fragments + MFMA: 2 k-steps of 32 ----
#pragma unroll
    for (int kk = 0; kk < 2; kk++) {
      bf16x8 af[4], bfr[4];
#pragma unroll
      for (int i = 0; i < 4; i++)
        af[i] = *(const bf16x8*)&As[(wr * 64 + i * 16 + l15) * 64 + kk * 32 + q4 * 8];
#pragma unroll
      for (int j = 0; j < 4; j++)
        bfr[j] = *(const bf16x8*)&Bs[(wc * 64 + j * 16 + l15) * 64 + kk * 32 + q4 * 8];
#pragma unroll
      for (int i = 0; i < 4; i++)
#pragma unroll
        for (int j = 0; j < 4; j++)
          acc[i][j] = __builtin_amdgcn_mfma_f32_16x16x32_bf16(af[i], bfr[j], acc[i][j], 0, 0, 0);
    }
  }

  const int col = l15, quad = q4;
#pragma unroll
  for (int j = 0; j < 4; j++) {
    const int gn = n0 + wc * 64 + j * 16 + col;
    const float bv = bias[gn];
#pragma unroll
    for (int i = 0; i < 4; i++) {
      const int gmb = m0 + wr * 64 + i * 16 + quad * 4;
#pragma unroll
      for (int rr = 0; rr < 4; rr++) {
        float val = acc[i][j][rr] + bv;
        const int gm = gmb + rr;
        if (MODE == 1) {
          outf[(size_t)gm * N + gn] = val;
        } else {
          const int b = gm >> 11, s = gm & (SEQ - 1);
          const int d = gn & (HDIM - 1);
          if (gn < 4096) {
            // fold attention scale 1/sqrt(128) into Q (commutes with RoPE)
            val *= 0.08838834764831845f;
            const int hh = gn >> 7;
            oq[((size_t)(b * NHEADS + hh) * SEQ + s) * HDIM + d] = f2b(val);
          } else if (gn < 5120) {
            const int hh = (gn - 4096) >> 7;
            ok[((size_t)(b * NKV + hh) * SEQ + s) * HDIM + d] = f2b(val);
          } else {
            const int hh = (gn - 5120) >> 7;
            ov[((size_t)(b * NKV + hh) * SEQ + s) * HDIM + d] = f2b(val);
          }
        }
      }
    }
  }
}

// ---------------------------------------------------------------------------
// RoPE in place on bf16 Q and K; cos/sin in fp32.
// ---------------------------------------------------------------------------
__global__ __launch_bounds__(256) void rope_kernel(u16* __restrict__ q, u16* __restrict__ kk,
                                                   int qrows, int totrows) {
  const int idx = blockIdx.x * 256 + threadIdx.x;
  const int row = idx >> 6;
  const int i   = idx & 63;
  if (row >= totrows) return;
  u16* base;
  int r;
  if (row < qrows) { base = q  + (size_t)row * HDIM;           r = row; }
  else             { base = kk + (size_t)(row - qrows) * HDIM; r = row - qrows; }
  const int s = r & (SEQ - 1);
  const float l2theta = 13.287712379549449f;  // log2(10000)
  const float inv = exp2f(-((float)(2 * i) * (1.0f / 128.0f)) * l2theta);
  const float ang = (float)s * inv;
  const float c  = cosf(ang);
  const float sn = sinf(ang);
  const u32 xv = *(const u32*)&base[2 * i];
  const float xr = b2f_lo(xv), xi = b2f_hi(xv);
  *(u32*)&base[2 * i] = pk(xr * c - xi * sn, xr * sn + xi * c);
}

// ---------------------------------------------------------------------------
// MFMA flash attention (causal, GQA group=4), SWAPPED-QK^T softmax.
// (unchanged from Round 3/4 -- 533 us; spill tuning deferred)
// ---------------------------------------------------------------------------
__global__ __launch_bounds__(256, 3) void attn_mfma(const u16* __restrict__ q,
                                                    const u16* __restrict__ k,
                                                    const u16* __restrict__ v,
                                                    u16* __restrict__ out) {
  __shared__ u16 Ks[64 * 136];       // [key][d], stride 136 u16 (272B)
  __shared__ u16 VtBuf[128 * 72];    // [d][key-swizzled], stride 72 u16 (144B)
  __shared__ u32 Ps32[4 * 32 * 36];  // per wave: [row][key-pair], stride 36 u32
  u32* Vt32 = (u32*)VtBuf;           // row stride 36 u32

  const int t    = threadIdx.x;
  const int lane = t & 63;
  const int w    = t >> 6;
  const int q4   = lane >> 4, l15 = lane & 15;
  const int qb   = 15 - (int)blockIdx.x;   // heavy blocks first
  const int h = blockIdx.y, b = blockIdx.z;
  const int m0 = qb * 128;
  const int mw = m0 + w * 32;              // wave's first q-row
  const int kvh = h >> 2;
  const u16* Qp = q + (size_t)(b * NHEADS + h) * SEQ * HDIM;
  const u16* Kp = k + (size_t)(b * NKV + kvh) * SEQ * HDIM;
  const u16* Vp = v + (size_t)(b * NKV + kvh) * SEQ * HDIM;

  // Q fragments (held in registers; Q already scaled by 1/sqrt(d))
  bf16x8 qf[2][4];
#pragma unroll
  for (int rt = 0; rt < 2; rt++)
#pragma unroll
    for (int kk = 0; kk < 4; kk++)
      qf[rt][kk] = *(const bf16x8*)&Qp[(size_t)(mw + rt * 16 + l15) * HDIM + kk * 32 + q4 * 8];

  f32x4 oacc[2][8] = {};
  float mrow[2], lrow[2];
  mrow[0] = mrow[1] = -1e30f;
  lrow[0] = lrow[1] = 0.f;

  u32* Pw32 = &Ps32[w * 32 * 36];

  const int nch = qb * 2 + 2;
  for (int kc = 0; kc < nch; kc++) {
    // ---- stage K: row-major, vector 16B units, coalesced (overlaps prev PV) ----
#pragma unroll
    for (int i = 0; i < 4; i++) {
      const int u = t + i * 256;           // 1024 units of 16B
      const int r = u >> 4, c = (u & 15) * 8;
      *(uint4*)&Ks[r * 136 + c] = *(const uint4*)&Kp[(size_t)(kc * 64 + r) * HDIM + c];
    }
    // ---- issue V loads now; consumed after softmax (latency hides under it) ----
    uint2 e0[4], e1[4];
#pragma unroll
    for (int i = 0; i < 4; i++) {
      const int tau = t + i * 256;         // 1024 tasks
      const int k2 = tau >> 5, dq = tau & 31;
      e0[i] = *(const uint2*)&Vp[(size_t)(kc * 64 + 2 * k2) * HDIM + dq * 4];
      e1[i] = *(const uint2*)&Vp[(size_t)(kc * 64 + 2 * k2 + 1) * HDIM + dq * 4];
    }
    __syncthreads();   // A: Ks published; prev-chunk Vt readers all done

    const bool part = (kc * 64 <= mw + 31);
    if (part) {
      const bool fullch = (kc * 64 + 63 <= mw);  // wave-uniform: no masking needed
      // ---- S^T = K Q^T (swapped operands) ----
      f32x4 sacc[2][4] = {};
      __builtin_amdgcn_s_setprio(1);
#pragma unroll
      for (int ct = 0; ct < 4; ct++) {
#pragma unroll
        for (int kk = 0; kk < 4; kk++) {
          const bf16x8 kb = *(const bf16x8*)&Ks[(ct * 16 + l15) * 136 + kk * 32 + q4 * 8];
          sacc[0][ct] = __builtin_amdgcn_mfma_f32_16x16x32_bf16(kb, qf[0][kk], sacc[0][ct], 0, 0, 0);
          sacc[1][ct] = __builtin_amdgcn_mfma_f32_16x16x32_bf16(kb, qf[1][kk], sacc[1][ct], 0, 0, 0);
        }
      }
      __builtin_amdgcn_s_setprio(0);
      // ---- softmax: lane owns 16 keys of q-row (rt*16+l15) ----
#pragma unroll
      for (int rt = 0; rt < 2; rt++) {
        float p[4][4];
        float cm[4];
        const int mm = mw + rt * 16 + l15;
#pragma unroll
        for (int ct = 0; ct < 4; ct++) {
#pragma unroll
          for (int rr = 0; rr < 4; rr++) {
            float s = sacc[rt][ct][rr];
            if (!fullch) {
              const int key = kc * 64 + ct * 16 + q4 * 4 + rr;
              s = (key <= mm) ? s : -1e30f;
            }
            p[ct][rr] = s;
          }
          cm[ct] = fmaxf(fmaxf(p[ct][0], p[ct][1]), fmaxf(p[ct][2], p[ct][3]));
        }
        float vmax = fmaxf(fmaxf(cm[0], cm[1]), fmaxf(cm[2], cm[3]));
        vmax = fmaxf(vmax, __shfl_xor(vmax, 16));
        vmax = fmaxf(vmax, __shfl_xor(vmax, 32));
        const float nm = fmaxf(mrow[rt], vmax);
        const float alpha = __expf(mrow[rt] - nm);
        mrow[rt] = nm;
        float cs[4];
#pragma unroll
        for (int ct = 0; ct < 4; ct++) {
#pragma unroll
          for (int rr = 0; rr < 4; rr++) p[ct][rr] = __expf(p[ct][rr] - nm);
          cs[ct] = (p[ct][0] + p[ct][1]) + (p[ct][2] + p[ct][3]);
        }
        lrow[rt] = lrow[rt] * alpha + ((cs[0] + cs[1]) + (cs[2] + cs[3]));
        // P -> LDS, packed u32 key-pairs (8B per ct); row spans u32 0..31
#pragma unroll
        for (int ct = 0; ct < 4; ct++) {
          uint2 w2;
          w2.x = pk(p[ct][0], p[ct][1]);
          w2.y = pk(p[ct][2], p[ct][3]);
          *(uint2*)&Pw32[(rt * 16 + l15) * 36 + ct * 8 + q4 * 2] = w2;
        }
        // alpha -> PV layout (row q4*4+rr) and rescale O
        float alT[4];
#pragma unroll
        for (int rr = 0; rr < 4; rr++) alT[rr] = __shfl(alpha, q4 * 4 + rr, 64);
#pragma unroll
        for (int dt = 0; dt < 8; dt++)
#pragma unroll
          for (int rr = 0; rr < 4; rr++) oacc[rt][dt][rr] *= alT[rr];
      }
    }
    // ---- commit V transposed: u32 key-pair packing + XOR group swizzle ----
#pragma unroll
    for (int i = 0; i < 4; i++) {
      const int tau = t + i * 256;
      const int k2 = tau >> 5, dq = tau & 31;
      u32 wj[4];
      wj[0] = (e0[i].x & 0xFFFFu) | (e1[i].x << 16);
      wj[1] = (e0[i].x >> 16)     | (e1[i].x & 0xFFFF0000u);
      wj[2] = (e0[i].y & 0xFFFFu) | (e1[i].y << 16);
      wj[3] = (e0[i].y >> 16)     | (e1[i].y & 0xFFFF0000u);
      const int g = k2 >> 2;
#pragma unroll
      for (int j = 0; j < 4; j++) {
        const int d = dq * 4 + j;
        const int gs = g ^ ((d >> 3) & 7);
        Vt32[d * 36 + gs * 4 + (k2 & 3)] = wj[j];
      }
    }
    __syncthreads();   // B: Vt published

    if (part) {
      // ---- O += P V ----
      __builtin_amdgcn_s_setprio(1);
#pragma unroll
      for (int kk2 = 0; kk2 < 2; kk2++) {
        bf16x8 pa[2];
        pa[0] = *(const bf16x8*)&Pw32[(l15) * 36 + kk2 * 16 + q4 * 4];
        pa[1] = *(const bf16x8*)&Pw32[(16 + l15) * 36 + kk2 * 16 + q4 * 4];
#pragma unroll
        for (int dt = 0; dt < 8; dt++) {
          const int d = dt * 16 + l15;
          const int gs = (kk2 * 4 + q4) ^ ((d >> 3) & 7);
          const bf16x8 vb = *(const bf16x8*)&Vt32[d * 36 + gs * 4];
          oacc[0][dt] = __builtin_amdgcn_mfma_f32_16x16x32_bf16(pa[0], vb, oacc[0][dt], 0, 0, 0);
          oacc[1][dt] = __builtin_amdgcn_mfma_f32_16x16x32_bf16(pa[1], vb, oacc[1][dt], 0, 0, 0);
        }
      }
      __builtin_amdgcn_s_setprio(0);
    }
  }

  // ---- epilogue: reduce l partials (4 q4-lanes), transpose to PV layout,
  //      O / l -> attn buffer [b][s][h*128+d] ----
#pragma unroll
  for (int rt = 0; rt < 2; rt++) {
    float ls = lrow[rt];
    ls += __shfl_xor(ls, 16);
    ls += __shfl_xor(ls, 32);
#pragma unroll
    for (int rr = 0; rr < 4; rr++) {
      const float lt = __shfl(ls, q4 * 4 + rr, 64);
      const float inv = 1.0f / lt;
      const int mm = mw + rt * 16 + q4 * 4 + rr;
      u16* op = &out[((size_t)(b * SEQ + mm)) * DMODEL + h * HDIM + l15];
#pragma unroll
      for (int dt = 0; dt < 8; dt++)
        op[dt * 16] = f2b(oacc[rt][dt][rr] * inv);
    }
  }
}

// ---------------------------------------------------------------------------
extern "C" void kernel_launch(void* const* d_in, const int* in_sizes, int n_in,
                              void* d_out, int out_size, void* d_ws, size_t ws_size,
                              hipStream_t stream) {
  const float* x     = (const float*)d_in[0];
  const float* w_qkv = (const float*)d_in[1];
  const float* b_qkv = (const float*)d_in[2];
  const float* w_o   = (const float*)d_in[3];
  const float* b_o   = (const float*)d_in[4];
  float* out = (float*)d_out;

  const size_t QN = (size_t)BATCH * NHEADS * SEQ * HDIM;   // 16.78M u16
  const size_t KN = (size_t)BATCH * NKV * SEQ * HDIM;      //  4.19M u16

  u16* q    = (u16*)d_ws;
  u16* k    = q + QN;
  u16* v    = k + KN;
  u16* attn = v + KN;
  u16* wb   = attn + QN;   // bf16 weight buffer: w_qkv (25.17M u16), reused for w_o
  u16* xb   = attn;        // bf16 x ALIASES attn: x is dead before attn_mfma writes

  const dim3 blk(256);

  // ---- convert x and w_qkv -> bf16 ----
  const int n8_x = BATCH * SEQ * DMODEL / 8;
  f32_to_bf16<<<dim3(n8_x / 256), blk, 0, stream>>>(x, xb, n8_x);
  const int n8_qkv = QKV_DIM * DMODEL / 8;
  f32_to_bf16<<<dim3(n8_qkv / 256), blk, 0, stream>>>(w_qkv, wb, n8_qkv);

  // ---- QKV GEMM: both operands bf16, full DMA staging ----
  gemm_bt2<0><<<dim3(QKV_DIM / 128, (BATCH * SEQ) / 128), blk, 0, stream>>>(
      xb, wb, b_qkv, nullptr, q, k, v, DMODEL, QKV_DIM);

  const int qrows = BATCH * NHEADS * SEQ;
  const int totrows = qrows + BATCH * NKV * SEQ;
  rope_kernel<<<dim3((totrows * 64) / 256), blk, 0, stream>>>(q, k, qrows, totrows);

  attn_mfma<<<dim3(SEQ / 128, NHEADS, BATCH), blk, 0, stream>>>(q, k, v, attn);

  // ---- convert w_o -> bf16 (reuses wb; w_qkv copy is dead now) ----
  const int n8_o = DMODEL * DMODEL / 8;
  f32_to_bf16<<<dim3(n8_o / 256), blk, 0, stream>>>(w_o, wb, n8_o);

  // ---- output GEMM: A = attn (bf16), B = wb (bf16), full DMA staging ----
  gemm_bt2<1><<<dim3(DMODEL / 128, (BATCH * SEQ) / 128), blk, 0, stream>>>(
      attn, wb, b_o, out, nullptr, nullptr, nullptr, DMODEL, DMODEL);
}

// Round 6
// 997.870 us; speedup vs baseline: 1.6699x; 1.2316x over previous
//
#include <hip/hip_runtime.h>

typedef unsigned short u16;
typedef unsigned int   u32;

#define BATCH   2
#define SEQ     2048
#define DMODEL  4096
#define NHEADS  32
#define NKV     8
#define HDIM    128
#define QKV_DIM 6144

typedef __bf16 bf16x8 __attribute__((ext_vector_type(8)));
typedef float  f32x4  __attribute__((ext_vector_type(4)));

__device__ __forceinline__ float b2f(u16 u) {
  u32 x = ((u32)u) << 16;
  return __builtin_bit_cast(float, x);
}
__device__ __forceinline__ u16 f2b(float f) {
  u32 x = __builtin_bit_cast(u32, f);
  x = (x + 0x7FFFu + ((x >> 16) & 1u)) >> 16;  // RNE
  return (u16)x;
}
__device__ __forceinline__ float b2f_lo(u32 p) { return __builtin_bit_cast(float, p << 16); }
__device__ __forceinline__ float b2f_hi(u32 p) { return __builtin_bit_cast(float, p & 0xFFFF0000u); }

__device__ __forceinline__ u32 pk(float a, float b) {
  return (u32)f2b(a) | ((u32)f2b(b) << 16);
}

// async 16B global -> LDS (DMA; no VGPR round-trip). Dest must be linear in
// lane order within a wave (wave-uniform base + lane*16) -- our staging is.
__device__ __forceinline__ void gload16(const u16* __restrict__ g, u16* l) {
  __builtin_amdgcn_global_load_lds(
      (const __attribute__((address_space(1))) unsigned int*)(const void*)g,
      (__attribute__((address_space(3))) unsigned int*)(void*)l,
      16, 0, 0);
}

// ---------------------------------------------------------------------------
// fp32 -> bf16 bulk convert, 8 elems/thread, vectorized. (weights + x)
// ---------------------------------------------------------------------------
__global__ __launch_bounds__(256) void f32_to_bf16(const float* __restrict__ in,
                                                   u16* __restrict__ out, int n8) {
  const int i = blockIdx.x * 256 + threadIdx.x;
  if (i >= n8) return;
  const float4* p = (const float4*)(in + (size_t)i * 8);
  const float4 a = p[0], b = p[1];
  uint4 r;
  r.x = pk(a.x, a.y); r.y = pk(a.z, a.w); r.z = pk(b.x, b.y); r.w = pk(b.z, b.w);
  ((uint4*)out)[i] = r;
}

// ---------------------------------------------------------------------------
// GEMM (m97 structure): C[m][n] = sum_k A[m][k] * W[n][k] + bias[n]
// 128x128 tile, 4 waves, BK=64, mfma_f32_16x16x32_bf16, fp32 accumulate.
// BOTH operands bf16, staged via global_load_lds dwordx4 into linear LDS.
// T1 XCD swizzle: nwg % 8 == 0 for both launches (1536, 1024) -> bijective
// simple form; each XCD gets a contiguous chunk = 4 M-rows of tiles, so the
// 4x1MB A-panels stay resident in that XCD's private L2 while B streams.
// MODE 0: scatter epilogue into bf16 Q/K/V [b,h,s,d]; Q pre-scaled by 1/sqrt(d).
// MODE 1: fp32 C + bias.
// ---------------------------------------------------------------------------
template <int MODE>
__global__ __launch_bounds__(256) void gemm_bt2(const u16* __restrict__ Ab,
                                                const u16* __restrict__ Bw,
                                                const float* __restrict__ bias,
                                                float* __restrict__ outf,
                                                u16* __restrict__ oq,
                                                u16* __restrict__ ok,
                                                u16* __restrict__ ov,
                                                int K, int N) {
  __shared__ u16 As[128 * 64];
  __shared__ u16 Bs[128 * 64];
  const int t    = threadIdx.x;
  const int lane = t & 63;
  const int wv   = t >> 6;
  const int wr   = wv >> 1, wc = wv & 1;
  const int q4   = lane >> 4, l15 = lane & 15;

  // ---- XCD-aware block swizzle (bijective: nwg % 8 == 0) ----
  const int nwgx = gridDim.x;
  const int nwg  = nwgx * gridDim.y;
  int bid = blockIdx.y * nwgx + blockIdx.x;
  const int cpx = nwg >> 3;
  bid = (bid & 7) * cpx + (bid >> 3);
  const int m0 = (bid / nwgx) * 128, n0 = (bid % nwgx) * 128;

  f32x4 acc[4][4] = {};

  for (int k0 = 0; k0 < K; k0 += 64) {
    __syncthreads();
    // ---- A + B tiles: 1024 x 16B units each via async DMA ----
#pragma unroll
    for (int i = 0; i < 4; i++) {
      const int u = t + i * 256;
      const int r = u >> 3, c8 = (u & 7) * 8;
      gload16(Bw + (size_t)(n0 + r) * K + k0 + c8, &Bs[u * 8]);
    }
#pragma unroll
    for (int i = 0; i < 4; i++) {
      const int u = t + i * 256;
      const int r = u >> 3, c8 = (u & 7) * 8;
      gload16(Ab + (size_t)(m0 + r) * K + k0 + c8, &As[u * 8]);
    }
    __syncthreads();   // drains vmcnt(0) -> LDS data visible

    // ---- fragments + MFMA: 2 k-steps of 32 ----
#pragma unroll
    for (int kk = 0; kk < 2; kk++) {
      bf16x8 af[4], bfr[4];
#pragma unroll
      for (int i = 0; i < 4; i++)
        af[i] = *(const bf16x8*)&As[(wr * 64 + i * 16 + l15) * 64 + kk * 32 + q4 * 8];
#pragma unroll
      for (int j = 0; j < 4; j++)
        bfr[j] = *(const bf16x8*)&Bs[(wc * 64 + j * 16 + l15) * 64 + kk * 32 + q4 * 8];
#pragma unroll
      for (int i = 0; i < 4; i++)
#pragma unroll
        for (int j = 0; j < 4; j++)
          acc[i][j] = __builtin_amdgcn_mfma_f32_16x16x32_bf16(af[i], bfr[j], acc[i][j], 0, 0, 0);
    }
  }

  const int col = l15, quad = q4;
#pragma unroll
  for (int j = 0; j < 4; j++) {
    const int gn = n0 + wc * 64 + j * 16 + col;
    const float bv = bias[gn];
#pragma unroll
    for (int i = 0; i < 4; i++) {
      const int gmb = m0 + wr * 64 + i * 16 + quad * 4;
#pragma unroll
      for (int rr = 0; rr < 4; rr++) {
        float val = acc[i][j][rr] + bv;
        const int gm = gmb + rr;
        if (MODE == 1) {
          outf[(size_t)gm * N + gn] = val;
        } else {
          const int b = gm >> 11, s = gm & (SEQ - 1);
          const int d = gn & (HDIM - 1);
          if (gn < 4096) {
            // fold attention scale 1/sqrt(128) into Q (commutes with RoPE)
            val *= 0.08838834764831845f;
            const int hh = gn >> 7;
            oq[((size_t)(b * NHEADS + hh) * SEQ + s) * HDIM + d] = f2b(val);
          } else if (gn < 5120) {
            const int hh = (gn - 4096) >> 7;
            ok[((size_t)(b * NKV + hh) * SEQ + s) * HDIM + d] = f2b(val);
          } else {
            const int hh = (gn - 5120) >> 7;
            ov[((size_t)(b * NKV + hh) * SEQ + s) * HDIM + d] = f2b(val);
          }
        }
      }
    }
  }
}

// ---------------------------------------------------------------------------
// RoPE in place on bf16 Q and K; cos/sin in fp32.
// ---------------------------------------------------------------------------
__global__ __launch_bounds__(256) void rope_kernel(u16* __restrict__ q, u16* __restrict__ kk,
                                                   int qrows, int totrows) {
  const int idx = blockIdx.x * 256 + threadIdx.x;
  const int row = idx >> 6;
  const int i   = idx & 63;
  if (row >= totrows) return;
  u16* base;
  int r;
  if (row < qrows) { base = q  + (size_t)row * HDIM;           r = row; }
  else             { base = kk + (size_t)(row - qrows) * HDIM; r = row - qrows; }
  const int s = r & (SEQ - 1);
  const float l2theta = 13.287712379549449f;  // log2(10000)
  const float inv = exp2f(-((float)(2 * i) * (1.0f / 128.0f)) * l2theta);
  const float ang = (float)s * inv;
  const float c  = cosf(ang);
  const float sn = sinf(ang);
  const u32 xv = *(const u32*)&base[2 * i];
  const float xr = b2f_lo(xv), xi = b2f_hi(xv);
  *(u32*)&base[2 * i] = pk(xr * c - xi * sn, xr * sn + xi * c);
}

// ---------------------------------------------------------------------------
// MFMA flash attention (causal, GQA group=4), SWAPPED-QK^T softmax.
// R5->R6: __launch_bounds__(256,2) -- the (256,3) pressure target at R3-R5
// produced VGPR_Count=84 with ~285 MB/launch scratch round-trips (FETCH+WRITE
// 325 MB vs ~85 MB ideal). Live state (~190 regs: oacc 64 + qf 32 + sacc 32 +
// V-prefetch 16 + temps) now fits; LDS 54272 -> 2 blocks/CU.
// ---------------------------------------------------------------------------
__global__ __launch_bounds__(256, 2) void attn_mfma(const u16* __restrict__ q,
                                                    const u16* __restrict__ k,
                                                    const u16* __restrict__ v,
                                                    u16* __restrict__ out) {
  __shared__ u16 Ks[64 * 136];       // [key][d], stride 136 u16 (272B)
  __shared__ u16 VtBuf[128 * 72];    // [d][key-swizzled], stride 72 u16 (144B)
  __shared__ u32 Ps32[4 * 32 * 36];  // per wave: [row][key-pair], stride 36 u32
  u32* Vt32 = (u32*)VtBuf;           // row stride 36 u32

  const int t    = threadIdx.x;
  const int lane = t & 63;
  const int w    = t >> 6;
  const int q4   = lane >> 4, l15 = lane & 15;
  const int qb   = 15 - (int)blockIdx.x;   // heavy blocks first
  const int h = blockIdx.y, b = blockIdx.z;
  const int m0 = qb * 128;
  const int mw = m0 + w * 32;              // wave's first q-row
  const int kvh = h >> 2;
  const u16* Qp = q + (size_t)(b * NHEADS + h) * SEQ * HDIM;
  const u16* Kp = k + (size_t)(b * NKV + kvh) * SEQ * HDIM;
  const u16* Vp = v + (size_t)(b * NKV + kvh) * SEQ * HDIM;

  // Q fragments (held in registers; Q already scaled by 1/sqrt(d))
  bf16x8 qf[2][4];
#pragma unroll
  for (int rt = 0; rt < 2; rt++)
#pragma unroll
    for (int kk = 0; kk < 4; kk++)
      qf[rt][kk] = *(const bf16x8*)&Qp[(size_t)(mw + rt * 16 + l15) * HDIM + kk * 32 + q4 * 8];

  f32x4 oacc[2][8] = {};
  float mrow[2], lrow[2];
  mrow[0] = mrow[1] = -1e30f;
  lrow[0] = lrow[1] = 0.f;

  u32* Pw32 = &Ps32[w * 32 * 36];

  const int nch = qb * 2 + 2;
  for (int kc = 0; kc < nch; kc++) {
    // ---- stage K: row-major, vector 16B units, coalesced (overlaps prev PV) ----
#pragma unroll
    for (int i = 0; i < 4; i++) {
      const int u = t + i * 256;           // 1024 units of 16B
      const int r = u >> 4, c = (u & 15) * 8;
      *(uint4*)&Ks[r * 136 + c] = *(const uint4*)&Kp[(size_t)(kc * 64 + r) * HDIM + c];
    }
    // ---- issue V loads now; consumed after softmax (latency hides under it) ----
    uint2 e0[4], e1[4];
#pragma unroll
    for (int i = 0; i < 4; i++) {
      const int tau = t + i * 256;         // 1024 tasks
      const int k2 = tau >> 5, dq = tau & 31;
      e0[i] = *(const uint2*)&Vp[(size_t)(kc * 64 + 2 * k2) * HDIM + dq * 4];
      e1[i] = *(const uint2*)&Vp[(size_t)(kc * 64 + 2 * k2 + 1) * HDIM + dq * 4];
    }
    __syncthreads();   // A: Ks published; prev-chunk Vt readers all done

    const bool part = (kc * 64 <= mw + 31);
    if (part) {
      const bool fullch = (kc * 64 + 63 <= mw);  // wave-uniform: no masking needed
      // ---- S^T = K Q^T (swapped operands) ----
      f32x4 sacc[2][4] = {};
      __builtin_amdgcn_s_setprio(1);
#pragma unroll
      for (int ct = 0; ct < 4; ct++) {
#pragma unroll
        for (int kk = 0; kk < 4; kk++) {
          const bf16x8 kb = *(const bf16x8*)&Ks[(ct * 16 + l15) * 136 + kk * 32 + q4 * 8];
          sacc[0][ct] = __builtin_amdgcn_mfma_f32_16x16x32_bf16(kb, qf[0][kk], sacc[0][ct], 0, 0, 0);
          sacc[1][ct] = __builtin_amdgcn_mfma_f32_16x16x32_bf16(kb, qf[1][kk], sacc[1][ct], 0, 0, 0);
        }
      }
      __builtin_amdgcn_s_setprio(0);
      // ---- softmax: lane owns 16 keys of q-row (rt*16+l15) ----
#pragma unroll
      for (int rt = 0; rt < 2; rt++) {
        float p[4][4];
        float cm[4];
        const int mm = mw + rt * 16 + l15;
#pragma unroll
        for (int ct = 0; ct < 4; ct++) {
#pragma unroll
          for (int rr = 0; rr < 4; rr++) {
            float s = sacc[rt][ct][rr];
            if (!fullch) {
              const int key = kc * 64 + ct * 16 + q4 * 4 + rr;
              s = (key <= mm) ? s : -1e30f;
            }
            p[ct][rr] = s;
          }
          cm[ct] = fmaxf(fmaxf(p[ct][0], p[ct][1]), fmaxf(p[ct][2], p[ct][3]));
        }
        float vmax = fmaxf(fmaxf(cm[0], cm[1]), fmaxf(cm[2], cm[3]));
        vmax = fmaxf(vmax, __shfl_xor(vmax, 16));
        vmax = fmaxf(vmax, __shfl_xor(vmax, 32));
        const float nm = fmaxf(mrow[rt], vmax);
        const float alpha = __expf(mrow[rt] - nm);
        mrow[rt] = nm;
        float cs[4];
#pragma unroll
        for (int ct = 0; ct < 4; ct++) {
#pragma unroll
          for (int rr = 0; rr < 4; rr++) p[ct][rr] = __expf(p[ct][rr] - nm);
          cs[ct] = (p[ct][0] + p[ct][1]) + (p[ct][2] + p[ct][3]);
        }
        lrow[rt] = lrow[rt] * alpha + ((cs[0] + cs[1]) + (cs[2] + cs[3]));
        // P -> LDS, packed u32 key-pairs (8B per ct); row spans u32 0..31
#pragma unroll
        for (int ct = 0; ct < 4; ct++) {
          uint2 w2;
          w2.x = pk(p[ct][0], p[ct][1]);
          w2.y = pk(p[ct][2], p[ct][3]);
          *(uint2*)&Pw32[(rt * 16 + l15) * 36 + ct * 8 + q4 * 2] = w2;
        }
        // alpha -> PV layout (row q4*4+rr) and rescale O
        float alT[4];
#pragma unroll
        for (int rr = 0; rr < 4; rr++) alT[rr] = __shfl(alpha, q4 * 4 + rr, 64);
#pragma unroll
        for (int dt = 0; dt < 8; dt++)
#pragma unroll
          for (int rr = 0; rr < 4; rr++) oacc[rt][dt][rr] *= alT[rr];
      }
    }
    // ---- commit V transposed: u32 key-pair packing + XOR group swizzle ----
#pragma unroll
    for (int i = 0; i < 4; i++) {
      const int tau = t + i * 256;
      const int k2 = tau >> 5, dq = tau & 31;
      u32 wj[4];
      wj[0] = (e0[i].x & 0xFFFFu) | (e1[i].x << 16);
      wj[1] = (e0[i].x >> 16)     | (e1[i].x & 0xFFFF0000u);
      wj[2] = (e0[i].y & 0xFFFFu) | (e1[i].y << 16);
      wj[3] = (e0[i].y >> 16)     | (e1[i].y & 0xFFFF0000u);
      const int g = k2 >> 2;
#pragma unroll
      for (int j = 0; j < 4; j++) {
        const int d = dq * 4 + j;
        const int gs = g ^ ((d >> 3) & 7);
        Vt32[d * 36 + gs * 4 + (k2 & 3)] = wj[j];
      }
    }
    __syncthreads();   // B: Vt published

    if (part) {
      // ---- O += P V ----
      __builtin_amdgcn_s_setprio(1);
#pragma unroll
      for (int kk2 = 0; kk2 < 2; kk2++) {
        bf16x8 pa[2];
        pa[0] = *(const bf16x8*)&Pw32[(l15) * 36 + kk2 * 16 + q4 * 4];
        pa[1] = *(const bf16x8*)&Pw32[(16 + l15) * 36 + kk2 * 16 + q4 * 4];
#pragma unroll
        for (int dt = 0; dt < 8; dt++) {
          const int d = dt * 16 + l15;
          const int gs = (kk2 * 4 + q4) ^ ((d >> 3) & 7);
          const bf16x8 vb = *(const bf16x8*)&Vt32[d * 36 + gs * 4];
          oacc[0][dt] = __builtin_amdgcn_mfma_f32_16x16x32_bf16(pa[0], vb, oacc[0][dt], 0, 0, 0);
          oacc[1][dt] = __builtin_amdgcn_mfma_f32_16x16x32_bf16(pa[1], vb, oacc[1][dt], 0, 0, 0);
        }
      }
      __builtin_amdgcn_s_setprio(0);
    }
  }

  // ---- epilogue: reduce l partials (4 q4-lanes), transpose to PV layout,
  //      O / l -> attn buffer [b][s][h*128+d] ----
#pragma unroll
  for (int rt = 0; rt < 2; rt++) {
    float ls = lrow[rt];
    ls += __shfl_xor(ls, 16);
    ls += __shfl_xor(ls, 32);
#pragma unroll
    for (int rr = 0; rr < 4; rr++) {
      const float lt = __shfl(ls, q4 * 4 + rr, 64);
      const float inv = 1.0f / lt;
      const int mm = mw + rt * 16 + q4 * 4 + rr;
      u16* op = &out[((size_t)(b * SEQ + mm)) * DMODEL + h * HDIM + l15];
#pragma unroll
      for (int dt = 0; dt < 8; dt++)
        op[dt * 16] = f2b(oacc[rt][dt][rr] * inv);
    }
  }
}

// ---------------------------------------------------------------------------
extern "C" void kernel_launch(void* const* d_in, const int* in_sizes, int n_in,
                              void* d_out, int out_size, void* d_ws, size_t ws_size,
                              hipStream_t stream) {
  const float* x     = (const float*)d_in[0];
  const float* w_qkv = (const float*)d_in[1];
  const float* b_qkv = (const float*)d_in[2];
  const float* w_o   = (const float*)d_in[3];
  const float* b_o   = (const float*)d_in[4];
  float* out = (float*)d_out;

  const size_t QN = (size_t)BATCH * NHEADS * SEQ * HDIM;   // 16.78M u16
  const size_t KN = (size_t)BATCH * NKV * SEQ * HDIM;      //  4.19M u16

  u16* q    = (u16*)d_ws;
  u16* k    = q + QN;
  u16* v    = k + KN;
  u16* attn = v + KN;
  u16* wb   = attn + QN;   // bf16 weight buffer: w_qkv (25.17M u16), reused for w_o
  u16* xb   = attn;        // bf16 x ALIASES attn: x is dead before attn_mfma writes

  const dim3 blk(256);

  // ---- convert x and w_qkv -> bf16 ----
  const int n8_x = BATCH * SEQ * DMODEL / 8;
  f32_to_bf16<<<dim3(n8_x / 256), blk, 0, stream>>>(x, xb, n8_x);
  const int n8_qkv = QKV_DIM * DMODEL / 8;
  f32_to_bf16<<<dim3(n8_qkv / 256), blk, 0, stream>>>(w_qkv, wb, n8_qkv);

  // ---- QKV GEMM: both operands bf16, full DMA staging ----
  gemm_bt2<0><<<dim3(QKV_DIM / 128, (BATCH * SEQ) / 128), blk, 0, stream>>>(
      xb, wb, b_qkv, nullptr, q, k, v, DMODEL, QKV_DIM);

  const int qrows = BATCH * NHEADS * SEQ;
  const int totrows = qrows + BATCH * NKV * SEQ;
  rope_kernel<<<dim3((totrows * 64) / 256), blk, 0, stream>>>(q, k, qrows, totrows);

  attn_mfma<<<dim3(SEQ / 128, NHEADS, BATCH), blk, 0, stream>>>(q, k, v, attn);

  // ---- convert w_o -> bf16 (reuses wb; w_qkv copy is dead now) ----
  const int n8_o = DMODEL * DMODEL / 8;
  f32_to_bf16<<<dim3(n8_o / 256), blk, 0, stream>>>(w_o, wb, n8_o);

  // ---- output GEMM: A = attn (bf16), B = wb (bf16), full DMA staging ----
  gemm_bt2<1><<<dim3(DMODEL / 128, (BATCH * SEQ) / 128), blk, 0, stream>>>(
      attn, wb, b_o, out, nullptr, nullptr, nullptr, DMODEL, DMODEL);
}